// Round 3
// baseline (4724.916 us; speedup 1.0000x reference)
//
#include <hip/hip_runtime.h>
#include <cmath>

// Problem constants
#define BB   16
#define LKK  64
#define LQQ  64
#define DD   300
#define HH   512
#define H2   1024
#define G4   2048
#define G8   4096
#define VV   10000

__device__ __forceinline__ float sigmoidf_(float x) { return 1.f / (1.f + expf(-x)); }

// ---- agent-scope (cross-XCD coherent) scalar access ----
__device__ __forceinline__ float ld_sc(const float* p) {
    return __hip_atomic_load(p, __ATOMIC_RELAXED, __HIP_MEMORY_SCOPE_AGENT);
}
__device__ __forceinline__ void st_sc(float* p, float v) {
    __hip_atomic_store(p, v, __ATOMIC_RELAXED, __HIP_MEMORY_SCOPE_AGENT);
}

// ---- grid barrier for 64 blocks (plain launch; all blocks co-resident by
// construction: 64 blocks <= 256 CUs, 1 block/CU via LDS+launch_bounds).
// Multi-wave-safe ordering: every wave drains its own vmcnt (h producers are
// waves 0/4/8/12), __syncthreads makes all drains precede the flag store by
// thread 0, wave 0 polls all 64 flags (1 per lane), then block-wide release.
__device__ __forceinline__ void gbar64(unsigned* flags, int wg, unsigned target) {
    asm volatile("s_waitcnt vmcnt(0)" ::: "memory");
    __syncthreads();
    if (threadIdx.x == 0)
        __hip_atomic_store(&flags[wg], target, __ATOMIC_RELAXED, __HIP_MEMORY_SCOPE_AGENT);
    if (threadIdx.x < 64) {
        for (;;) {
            unsigned f = __hip_atomic_load(&flags[threadIdx.x],
                                           __ATOMIC_RELAXED, __HIP_MEMORY_SCOPE_AGENT);
            if (__all((int)(f >= target))) break;
            __builtin_amdgcn_s_sleep(1);
        }
    }
    __syncthreads();
}

// ---------------- reverse source indices + barrier-flag init -----------------
__global__ void rev_idx_kernel(const int* __restrict__ src, int* __restrict__ rev,
                               unsigned* __restrict__ bars) {
    int tid = blockIdx.x * blockDim.x + threadIdx.x;
    if (tid < 512) bars[tid] = 0u;
    if (tid < BB * LKK) {
        int b = tid / LKK, t = tid % LKK;
        rev[tid] = src[b * LKK + (LKK - 1 - t)];
    }
}

// ---------------- split-bf16 MFMA NT GEMM ------------------------------------
// C[m,n] = sum_k A[m,k]*Bw[n,k] + bias[n]; A row-major [M,K] (or gathered via
// gidx); Bw row-major [N,K]. M multiple of 128 (always 1024 here). fp32 inputs
// are split into bf16 hi+lo; acc += Ah*Bh + Ah*Bl + Al*Bh (fp32 MFMA accum)
// gives ~fp32 accuracy at ~1/3 the bf16 MFMA rate. act: 0=none, 1=tanh.
typedef __attribute__((ext_vector_type(8))) short bfrag8;   // 8 bf16 (4 VGPR)
typedef __attribute__((ext_vector_type(4))) float facc4;    // 4 fp32 accum

__device__ __forceinline__ unsigned short f2bf(float x) {
    unsigned u = __float_as_uint(x);
    unsigned r = (u + 0x7fffu + ((u >> 16) & 1u)) >> 16;   // round-to-nearest-even
    return (unsigned short)r;
}

#define ASTR 40   // LDS row stride in bf16 elems: 80B rows -> 16B-aligned b128
                  // reads, 16-row column access covers all 32 banks evenly

__global__ __launch_bounds__(256)
void gemm_mfma128(const float* __restrict__ A, const int* __restrict__ gidx, int lda,
                  const float* __restrict__ Bw, int ldb,
                  const float* __restrict__ bias,
                  float* __restrict__ C, int ldc,
                  int N, int K, int act) {
    __shared__ __align__(16) short Ah[128 * ASTR];
    __shared__ __align__(16) short Al[128 * ASTR];
    __shared__ __align__(16) short Bh[128 * ASTR];
    __shared__ __align__(16) short Bl[128 * ASTR];
    int m0 = blockIdx.x * 128;
    int n0 = blockIdx.y * 128;
    int tid = threadIdx.x;
    int lane = tid & 63, w = tid >> 6;
    int wr = w >> 1, wc = w & 1;                  // wave's 64x64 quadrant
    int fr = lane & 15, fg = lane >> 4;           // fragment row/col, k-group

    // staging coords: thread -> (row sr, 16-col half sc)
    int sr = tid >> 1, sc = (tid & 1) << 4;
    long abase = gidx ? (long)gidx[m0 + sr] * lda : (long)(m0 + sr) * lda;
    int gn = n0 + sr;
    bool bval = gn < N;
    long bbase = (long)gn * ldb;

    facc4 acc[4][4] = {};

    for (int k0 = 0; k0 < K; k0 += 32) {
        // ---- stage A tile (fp32 -> bf16 hi/lo) ----
        {
            float v[16];
            if (k0 + sc + 16 <= K) {
                const float* ap = A + abase + k0 + sc;
                float4 t0 = *(const float4*)(ap + 0);
                float4 t1 = *(const float4*)(ap + 4);
                float4 t2 = *(const float4*)(ap + 8);
                float4 t3 = *(const float4*)(ap + 12);
                v[0]=t0.x; v[1]=t0.y; v[2]=t0.z;  v[3]=t0.w;
                v[4]=t1.x; v[5]=t1.y; v[6]=t1.z;  v[7]=t1.w;
                v[8]=t2.x; v[9]=t2.y; v[10]=t2.z; v[11]=t2.w;
                v[12]=t3.x; v[13]=t3.y; v[14]=t3.z; v[15]=t3.w;
            } else {
#pragma unroll
                for (int c = 0; c < 16; c++) {
                    int k = k0 + sc + c;
                    v[c] = (k < K) ? A[abase + k] : 0.f;
                }
            }
            bfrag8 h0, h1, l0, l1;
#pragma unroll
            for (int c = 0; c < 8; c++) {
                unsigned short hb = f2bf(v[c]);
                float hf = __uint_as_float(((unsigned)hb) << 16);
                h0[c] = (short)hb; l0[c] = (short)f2bf(v[c] - hf);
            }
#pragma unroll
            for (int c = 0; c < 8; c++) {
                unsigned short hb = f2bf(v[8 + c]);
                float hf = __uint_as_float(((unsigned)hb) << 16);
                h1[c] = (short)hb; l1[c] = (short)f2bf(v[8 + c] - hf);
            }
            *(bfrag8*)&Ah[sr * ASTR + sc]     = h0;
            *(bfrag8*)&Ah[sr * ASTR + sc + 8] = h1;
            *(bfrag8*)&Al[sr * ASTR + sc]     = l0;
            *(bfrag8*)&Al[sr * ASTR + sc + 8] = l1;
        }
        // ---- stage B tile ----
        {
            float v[16];
            if (bval && (k0 + sc + 16 <= K)) {
                const float* bp = Bw + bbase + k0 + sc;
                float4 t0 = *(const float4*)(bp + 0);
                float4 t1 = *(const float4*)(bp + 4);
                float4 t2 = *(const float4*)(bp + 8);
                float4 t3 = *(const float4*)(bp + 12);
                v[0]=t0.x; v[1]=t0.y; v[2]=t0.z;  v[3]=t0.w;
                v[4]=t1.x; v[5]=t1.y; v[6]=t1.z;  v[7]=t1.w;
                v[8]=t2.x; v[9]=t2.y; v[10]=t2.z; v[11]=t2.w;
                v[12]=t3.x; v[13]=t3.y; v[14]=t3.z; v[15]=t3.w;
            } else {
#pragma unroll
                for (int c = 0; c < 16; c++) {
                    int k = k0 + sc + c;
                    v[c] = (bval && k < K) ? Bw[bbase + k] : 0.f;
                }
            }
            bfrag8 h0, h1, l0, l1;
#pragma unroll
            for (int c = 0; c < 8; c++) {
                unsigned short hb = f2bf(v[c]);
                float hf = __uint_as_float(((unsigned)hb) << 16);
                h0[c] = (short)hb; l0[c] = (short)f2bf(v[c] - hf);
            }
#pragma unroll
            for (int c = 0; c < 8; c++) {
                unsigned short hb = f2bf(v[8 + c]);
                float hf = __uint_as_float(((unsigned)hb) << 16);
                h1[c] = (short)hb; l1[c] = (short)f2bf(v[8 + c] - hf);
            }
            *(bfrag8*)&Bh[sr * ASTR + sc]     = h0;
            *(bfrag8*)&Bh[sr * ASTR + sc + 8] = h1;
            *(bfrag8*)&Bl[sr * ASTR + sc]     = l0;
            *(bfrag8*)&Bl[sr * ASTR + sc + 8] = l1;
        }
        __syncthreads();

        // ---- fragment loads: lane holds 8 contiguous k at row/col = fr ----
        bfrag8 ah[4], al[4], bh[4], bl[4];
#pragma unroll
        for (int i = 0; i < 4; i++) {
            int ar = wr * 64 + i * 16 + fr;
            ah[i] = *(const bfrag8*)&Ah[ar * ASTR + fg * 8];
            al[i] = *(const bfrag8*)&Al[ar * ASTR + fg * 8];
            int br = wc * 64 + i * 16 + fr;
            bh[i] = *(const bfrag8*)&Bh[br * ASTR + fg * 8];
            bl[i] = *(const bfrag8*)&Bl[br * ASTR + fg * 8];
        }
#pragma unroll
        for (int i = 0; i < 4; i++)
#pragma unroll
            for (int j = 0; j < 4; j++) {
                acc[i][j] = __builtin_amdgcn_mfma_f32_16x16x32_bf16(ah[i], bh[j], acc[i][j], 0, 0, 0);
                acc[i][j] = __builtin_amdgcn_mfma_f32_16x16x32_bf16(ah[i], bl[j], acc[i][j], 0, 0, 0);
                acc[i][j] = __builtin_amdgcn_mfma_f32_16x16x32_bf16(al[i], bh[j], acc[i][j], 0, 0, 0);
            }
        __syncthreads();
    }

    // ---- epilogue: C/D layout col=lane&15, row=(lane>>4)*4+q ----
#pragma unroll
    for (int i = 0; i < 4; i++) {
        int row = m0 + wr * 64 + i * 16 + fg * 4;
#pragma unroll
        for (int j = 0; j < 4; j++) {
            int col = n0 + wc * 64 + j * 16 + fr;
            if (col < N) {
                float bz = bias[col];
#pragma unroll
                for (int q = 0; q < 4; q++) {
                    float vv = acc[i][j][q] + bz;
                    if (act == 1) vv = tanhf(vv);
                    C[(long)(row + q) * ldc + col] = vv;
                }
            }
        }
    }
}

// ============ persistent encoder recurrence (fwd+bwd), 64 blocks x 1024 =====
// Each 256-thread quarter executes the old 256-thread block's code for
// virtual wg v = blockIdx*4 + quarter (identical FLOP order => identical
// results). Blocks 0-31 are dir0, 32-63 dir1 (v<128 <=> dir0). hs is staged
// once per block; 4 waves/SIMD give intra-SIMD latency hiding.
__global__ __launch_bounds__(1024, 1)
void enc_recur(const float* __restrict__ xg_f, const float* __restrict__ xg_b,
               const float* __restrict__ Wf, const float* __restrict__ Wb,
               float* __restrict__ hglob, float* __restrict__ enc_out,
               float* __restrict__ encc, unsigned* __restrict__ flags) {
    __shared__ float hs[HH * 16];       // 32 KB (this dir's h)
    __shared__ float gbuf[4][BB * 17];
    int wg  = blockIdx.x;
    int tid = threadIdx.x;
    int q    = tid >> 8;                // quarter index = sub-block
    int qtid = tid & 255;
    int v    = wg * 4 + q;              // virtual wg 0..255
    int dir  = v >> 7;                  // uniform within a block
    int j0   = (v & 127) * 4;
    int ks   = qtid & 31;
    int tile = qtid >> 5;
    int bh   = tile >> 2;
    int nql  = (tile & 3) << 2;
    int gate = tile & 3;
    int sw   = (ks >> 2) & 3;
    const float* W  = dir ? Wb : Wf;    // [2048][512]
    const float* xg = dir ? xg_b : xg_f;

    float wreg[4][16];
#pragma unroll
    for (int jn = 0; jn < 4; jn++) {
        const float* wrow = W + (long)(gate * HH + j0 + jn) * HH;
#pragma unroll
        for (int j = 0; j < 16; j++) wreg[jn][j] = wrow[ks + 32 * j];
    }

    int ub = qtid & 15, ujj = qtid >> 4;
    float creg = 0.f;
    float4* hsv = (float4*)hs;

    for (int t = 0; t < LKK; t++) {
        if (t == 0) {
            for (int i = tid; i < HH * 16; i += 1024) hs[i] = 0.f;
        } else {
            const float* hg = hglob + (long)((dir << 1) | (t & 1)) * (HH * 16);
            float vv[8];
#pragma unroll
            for (int u = 0; u < 8; u++) vv[u] = ld_sc(hg + tid + u * 1024);
#pragma unroll
            for (int u = 0; u < 8; u++) {
                int e = tid + u * 1024;
                int jj = e >> 4, b = e & 15;
                hs[(jj << 4) + ((((b >> 2) ^ ((jj >> 2) & 3))) << 2) + (b & 3)] = vv[u];
            }
        }
        float4 xr[8];
        if (ks == 0) {
#pragma unroll
            for (int i = 0; i < 8; i++) {
                const float* xp = xg + (long)((bh * 8 + i) * LKK + t) * G4 + gate * HH + j0;
                xr[i] = *(const float4*)xp;
            }
        }
        __syncthreads();

        float acc[8][4];
#pragma unroll
        for (int i = 0; i < 8; i++)
#pragma unroll
            for (int jn = 0; jn < 4; jn++) acc[i][jn] = 0.f;
#pragma unroll
        for (int j = 0; j < 16; j++) {
            int k = ks + 32 * j;
            float4 h0 = hsv[k * 4 + ((bh * 2 + 0) ^ sw)];
            float4 h1 = hsv[k * 4 + ((bh * 2 + 1) ^ sw)];
#pragma unroll
            for (int jn = 0; jn < 4; jn++) {
                float w = wreg[jn][j];
                acc[0][jn] += h0.x * w; acc[1][jn] += h0.y * w;
                acc[2][jn] += h0.z * w; acc[3][jn] += h0.w * w;
                acc[4][jn] += h1.x * w; acc[5][jn] += h1.y * w;
                acc[6][jn] += h1.z * w; acc[7][jn] += h1.w * w;
            }
        }
#pragma unroll
        for (int i = 0; i < 8; i++)
#pragma unroll
            for (int jn = 0; jn < 4; jn++) {
                float vv = acc[i][jn];
                vv += __shfl_xor(vv, 1, 64);  vv += __shfl_xor(vv, 2, 64);
                vv += __shfl_xor(vv, 4, 64);  vv += __shfl_xor(vv, 8, 64);
                vv += __shfl_xor(vv, 16, 64);
                acc[i][jn] = vv;
            }
        if (ks == 0) {
#pragma unroll
            for (int i = 0; i < 8; i++)
#pragma unroll
                for (int jn = 0; jn < 4; jn++)
                    gbuf[q][(bh * 8 + i) * 17 + nql + jn] = acc[i][jn] + ((const float*)&xr[i])[jn];
        }
        __syncthreads();

        if (qtid < 64) {
            int j = j0 + ujj;
            float gi = gbuf[q][ub * 17 + 0  + ujj];
            float gf = gbuf[q][ub * 17 + 4  + ujj];
            float gg = gbuf[q][ub * 17 + 8  + ujj];
            float go = gbuf[q][ub * 17 + 12 + ujj];
            float cv = sigmoidf_(gf) * creg + sigmoidf_(gi) * tanhf(gg);
            creg = cv;
            float hv = sigmoidf_(go) * tanhf(cv);
            st_sc(&hglob[(long)((dir << 1) | ((t + 1) & 1)) * (HH * 16) + j * 16 + ub], hv);
            int kpos = dir ? (LKK - 1 - t) : t;
            enc_out[(long)(ub * LKK + kpos) * H2 + dir * HH + j] = hv;
            if (t == LKK - 1) encc[(dir * BB + ub) * HH + j] = creg;
        }
        if (t < LKK - 1) gbar64(flags, wg, (unsigned)(t + 1));
    }
}

// ============ persistent decoder recurrence, 64 blocks x 1024 ===============
__global__ __launch_bounds__(1024, 1)
void dec_recur(const float* __restrict__ xg_d, const float* __restrict__ Wd,
               const float* __restrict__ enc_out, const float* __restrict__ encc,
               float* __restrict__ hglob, float* __restrict__ Qout,
               unsigned* __restrict__ flags) {
    __shared__ float hs[HH * 16];       // 32 KB (one half of h)
    __shared__ float gbuf[4][BB * 17];
    int wg  = blockIdx.x;
    int tid = threadIdx.x;
    int q    = tid >> 8;
    int qtid = tid & 255;
    int v    = wg * 4 + q;              // virtual wg 0..255
    int j0   = v * 4;
    int ks   = qtid & 31;
    int tile = qtid >> 5;
    int bh   = tile >> 2;
    int nql  = (tile & 3) << 2;
    int gate = tile & 3;
    int sw   = (ks >> 2) & 3;

    float wreg[4][32];
#pragma unroll
    for (int jn = 0; jn < 4; jn++) {
        const float* wrow = Wd + (long)(gate * H2 + j0 + jn) * H2;
#pragma unroll
        for (int j = 0; j < 32; j++) wreg[jn][j] = wrow[ks + 32 * j];
    }

    int ub = qtid & 15, ujj = qtid >> 4;
    float creg = 0.f;
    if (qtid < 64) {
        int j = j0 + ujj;
        creg = ((j & 1) == 0) ? encc[ub * HH + (j >> 1)]
                              : encc[(BB + ub) * HH + (j >> 1)];
    }
    float4* hsv = (float4*)hs;

    for (int t = 0; t < LQQ; t++) {
        float4 xr[8];
        if (ks == 0) {
#pragma unroll
            for (int i = 0; i < 8; i++) {
                const float* xp = xg_d + (long)((bh * 8 + i) * LQQ + t) * G8 + gate * H2 + j0;
                xr[i] = *(const float4*)xp;
            }
        }
        float acc[8][4];
#pragma unroll
        for (int i = 0; i < 8; i++)
#pragma unroll
            for (int jn = 0; jn < 4; jn++) acc[i][jn] = 0.f;

#pragma unroll
        for (int half = 0; half < 2; half++) {
            if (t == 0) {
                for (int e = tid; e < HH * 16; e += 1024) {
                    int kl = e >> 4, b = e & 15;
                    int k = half * HH + kl;
                    float hv = ((k & 1) == 0)
                        ? enc_out[(long)(b * LKK + (LKK - 1)) * H2 + (k >> 1)]
                        : enc_out[(long)(b * LKK) * H2 + HH + (k >> 1)];
                    hs[(kl << 4) + ((((b >> 2) ^ ((kl >> 2) & 3))) << 2) + (b & 3)] = hv;
                }
            } else {
                const float* hg = hglob + (long)(t & 1) * (H2 * 16) + (long)half * (HH * 16);
                float vv[8];
#pragma unroll
                for (int u = 0; u < 8; u++) vv[u] = ld_sc(hg + tid + u * 1024);
#pragma unroll
                for (int u = 0; u < 8; u++) {
                    int e = tid + u * 1024;
                    int kl = e >> 4, b = e & 15;
                    hs[(kl << 4) + ((((b >> 2) ^ ((kl >> 2) & 3))) << 2) + (b & 3)] = vv[u];
                }
            }
            __syncthreads();
#pragma unroll
            for (int jj2 = 0; jj2 < 16; jj2++) {
                int j = half * 16 + jj2;
                int kl = ks + 32 * jj2;
                float4 h0 = hsv[kl * 4 + ((bh * 2 + 0) ^ sw)];
                float4 h1 = hsv[kl * 4 + ((bh * 2 + 1) ^ sw)];
#pragma unroll
                for (int jn = 0; jn < 4; jn++) {
                    float w = wreg[jn][j];
                    acc[0][jn] += h0.x * w; acc[1][jn] += h0.y * w;
                    acc[2][jn] += h0.z * w; acc[3][jn] += h0.w * w;
                    acc[4][jn] += h1.x * w; acc[5][jn] += h1.y * w;
                    acc[6][jn] += h1.z * w; acc[7][jn] += h1.w * w;
                }
            }
            __syncthreads();
        }

#pragma unroll
        for (int i = 0; i < 8; i++)
#pragma unroll
            for (int jn = 0; jn < 4; jn++) {
                float vv = acc[i][jn];
                vv += __shfl_xor(vv, 1, 64);  vv += __shfl_xor(vv, 2, 64);
                vv += __shfl_xor(vv, 4, 64);  vv += __shfl_xor(vv, 8, 64);
                vv += __shfl_xor(vv, 16, 64);
                acc[i][jn] = vv;
            }
        if (ks == 0) {
#pragma unroll
            for (int i = 0; i < 8; i++)
#pragma unroll
                for (int jn = 0; jn < 4; jn++)
                    gbuf[q][(bh * 8 + i) * 17 + nql + jn] = acc[i][jn] + ((const float*)&xr[i])[jn];
        }
        __syncthreads();

        if (qtid < 64) {
            int j = j0 + ujj;
            float gi = gbuf[q][ub * 17 + 0  + ujj];
            float gf = gbuf[q][ub * 17 + 4  + ujj];
            float gg = gbuf[q][ub * 17 + 8  + ujj];
            float go = gbuf[q][ub * 17 + 12 + ujj];
            float cv = sigmoidf_(gf) * creg + sigmoidf_(gi) * tanhf(gg);
            creg = cv;
            float hv = sigmoidf_(go) * tanhf(cv);
            st_sc(&hglob[(long)((t + 1) & 1) * (H2 * 16) + j * 16 + ub], hv);
            Qout[(long)(ub * LQQ + t) * H2 + j] = hv;
        }
        if (t < LQQ - 1) gbar64(flags, wg, (unsigned)(t + 1));
    }
}

// ---------------- attention + concat[ctx, Q] ---------------------------------
__global__ __launch_bounds__(256)
void attention_kernel(const float* __restrict__ Qm, const float* __restrict__ Km,
                      const float* __restrict__ Vm, const int* __restrict__ source,
                      float* __restrict__ concatBuf) {
    int b = blockIdx.x >> 6;
    int q = blockIdx.x & 63;
    int tid = threadIdx.x;
    __shared__ float qrow[H2];
    __shared__ float part[LKK][4];
    __shared__ float aw[LKK];

    for (int i = tid; i < H2; i += 256) qrow[i] = Qm[(long)(b * LQQ + q) * H2 + i];
    __syncthreads();

    int k = tid >> 2, p = tid & 3;
    {
        const float* krow = Km + (long)(b * LKK + k) * H2 + p * 256;
        const float* qp = qrow + p * 256;
        float s = 0.f;
#pragma unroll 4
        for (int i = 0; i < 256; i++) s += qp[i] * krow[i];
        part[k][p] = s;
    }
    __syncthreads();
    if (tid < 64) {
        float sc = part[tid][0] + part[tid][1] + part[tid][2] + part[tid][3];
        bool masked = (source[b * LKK + tid] == 0);
        float m = masked ? -INFINITY : sc;
#pragma unroll
        for (int o = 32; o >= 1; o >>= 1) m = fmaxf(m, __shfl_xor(m, o, 64));
        float e = masked ? 0.f : expf(sc - m);
        float sum = e;
#pragma unroll
        for (int o = 32; o >= 1; o >>= 1) sum += __shfl_xor(sum, o, 64);
        aw[tid] = e / sum;
    }
    __syncthreads();

    for (int c = tid; c < H2; c += 256) {
        float acc = 0.f;
#pragma unroll 8
        for (int kk = 0; kk < LKK; kk++) acc += aw[kk] * Vm[(long)(b * LKK + kk) * H2 + c];
        long row = (long)(b * LQQ + q) * (2 * H2);
        concatBuf[row + c] = acc;
        concatBuf[row + H2 + c] = qrow[c];
    }
}

// ---------------- host launcher ----------------------------------------------
extern "C" void kernel_launch(void* const* d_in, const int* in_sizes, int n_in,
                              void* d_out, int out_size, void* d_ws, size_t ws_size,
                              hipStream_t stream) {
    const int*   src       = (const int*)  d_in[0];
    const int*   prev      = (const int*)  d_in[1];
    const float* emb       = (const float*)d_in[2];
    const float* enc_f_Wih = (const float*)d_in[3];
    const float* enc_f_Whh = (const float*)d_in[4];
    const float* enc_f_b   = (const float*)d_in[5];
    const float* enc_b_Wih = (const float*)d_in[6];
    const float* enc_b_Whh = (const float*)d_in[7];
    const float* enc_b_b   = (const float*)d_in[8];
    const float* dec_Wih   = (const float*)d_in[9];
    const float* dec_Whh   = (const float*)d_in[10];
    const float* dec_b     = (const float*)d_in[11];
    const float* k_W  = (const float*)d_in[12];
    const float* k_b  = (const float*)d_in[13];
    const float* v_W  = (const float*)d_in[14];
    const float* v_b  = (const float*)d_in[15];
    const float* fc1_W = (const float*)d_in[16];
    const float* fc1_b = (const float*)d_in[17];
    const float* fc2_W = (const float*)d_in[18];
    const float* fc2_b = (const float*)d_in[19];
    float* out = (float*)d_out;

    // workspace layout (floats) — kept identical to prior rounds
    float* p = (float*)d_ws;
    float* xg_f    = p; p += (long)BB * LKK * G4;
    float* xg_b    = p; p += (long)BB * LKK * G4;
    float* xg_d    = p; p += (long)BB * LQQ * G8;
    float* enc_out = p; p += (long)BB * LKK * H2;
    float* encc    = p; p += 2L * BB * HH;
    float* hg_enc  = p; p += 2L * 2 * HH * 16;
    float* hg_dec  = p; p += 2L * H2 * 16;
    float* Qbuf    = p; p += (long)BB * LQQ * H2;
    float* Kbuf    = p; p += (long)BB * LKK * H2;
    float* Vbuf    = p; p += (long)BB * LKK * H2;
    float* concatB = p; p += (long)BB * LQQ * 2 * H2;
    float* fc1out  = p; p += (long)BB * LQQ * H2;
    int*   rev     = (int*)p; p += (BB * LKK);
    unsigned* bars = (unsigned*)p; p += 512;     // flags: enc [0:64), dec [256:320)

    // 1) reversed source indices + barrier-flag zero
    rev_idx_kernel<<<4, 256, 0, stream>>>(src, rev, bars);

    // 2) xg precomputes (gathered-embedding GEMMs), M = 1024
    gemm_mfma128<<<dim3(8, G4 / 128), 256, 0, stream>>>(emb, src, DD, enc_f_Wih, DD,
                                                        enc_f_b, xg_f, G4, G4, DD, 0);
    gemm_mfma128<<<dim3(8, G4 / 128), 256, 0, stream>>>(emb, rev, DD, enc_b_Wih, DD,
                                                        enc_b_b, xg_b, G4, G4, DD, 0);
    gemm_mfma128<<<dim3(8, G8 / 128), 256, 0, stream>>>(emb, prev, DD, dec_Wih, DD,
                                                        dec_b, xg_d, G8, G8, DD, 0);

    // 3) encoder recurrence: persistent kernel, 64 blocks x 1024 threads
    enc_recur<<<dim3(64), dim3(1024), 0, stream>>>(xg_f, xg_b, enc_f_Whh, enc_b_Whh,
                                                   hg_enc, enc_out, encc, bars);

    // 4) K/V projections
    gemm_mfma128<<<dim3(8, 8), 256, 0, stream>>>(enc_out, nullptr, H2, k_W, H2,
                                                 k_b, Kbuf, H2, H2, H2, 0);
    gemm_mfma128<<<dim3(8, 8), 256, 0, stream>>>(enc_out, nullptr, H2, v_W, H2,
                                                 v_b, Vbuf, H2, H2, H2, 0);

    // 5) decoder recurrence: persistent kernel, 64 blocks x 1024 threads
    dec_recur<<<dim3(64), dim3(1024), 0, stream>>>(xg_d, dec_Whh, enc_out, encc,
                                                   hg_dec, Qbuf, bars + 256);

    // 6) attention -> concat[ctx, Q]
    attention_kernel<<<BB * LQQ, 256, 0, stream>>>(Qbuf, Kbuf, Vbuf, src, concatB);

    // 7) fc1 with tanh
    gemm_mfma128<<<dim3(8, 8), 256, 0, stream>>>(concatB, nullptr, 2 * H2, fc1_W, 2 * H2,
                                                 fc1_b, fc1out, H2, H2, 2 * H2, 1);

    // 8) fc2 -> output [1024, 10000]
    gemm_mfma128<<<dim3(8, (VV + 127) / 128), 256, 0, stream>>>(fc1out, nullptr, H2, fc2_W, H2,
                                                                fc2_b, out, VV, VV, H2, 0);
}

// Round 4
// 1868.040 us; speedup vs baseline: 2.5293x; 2.5293x over previous
//
#include <hip/hip_runtime.h>
#include <cmath>

// Problem constants
#define BB   16
#define LKK  64
#define LQQ  64
#define DD   300
#define HH   512
#define H2   1024
#define G4   2048
#define G8   4096
#define VV   10000

__device__ __forceinline__ float sigmoidf_(float x) { return 1.f / (1.f + expf(-x)); }

typedef __attribute__((ext_vector_type(4))) float    f4_;
typedef __attribute__((ext_vector_type(4))) unsigned u4_;

// ---- agent-scope (cross-XCD coherent) scalar access ----
__device__ __forceinline__ float ld_sc(const float* p) {
    return __hip_atomic_load(p, __ATOMIC_RELAXED, __HIP_MEMORY_SCOPE_AGENT);
}
__device__ __forceinline__ void st_sc(float* p, float v) {
    __hip_atomic_store(p, v, __ATOMIC_RELAXED, __HIP_MEMORY_SCOPE_AGENT);
}

// ---- wide agent-coherent loads: global_load_dwordx4 with sc0 sc1 bypasses
// L1/L2 so cross-XCD-produced data is fetched fresh, but goes down the normal
// VMEM path (full coalescing, 4x fewer requests than per-dword atomic loads).
// Caller MUST s_waitcnt vmcnt(0) + sched_barrier(0) before using the result
// (rule: compiler will otherwise hoist uses past the inline-asm wait).
__device__ __forceinline__ f4_ ld4_sc(const float* p) {
    f4_ r;
    asm volatile("global_load_dwordx4 %0, %1, off sc0 sc1" : "=v"(r) : "v"(p));
    return r;
}
__device__ __forceinline__ u4_ ld4u_sc(const unsigned* p) {
    u4_ r;
    asm volatile("global_load_dwordx4 %0, %1, off sc0 sc1" : "=v"(r) : "v"(p));
    return r;
}
__device__ __forceinline__ void wait_vm0() {
    asm volatile("s_waitcnt vmcnt(0)" ::: "memory");
    __builtin_amdgcn_sched_barrier(0);
}

// ---- contention-free grid barrier: per-wg flag stores (no RMW serialization),
// wave-0 polls all 256 flags (one dwordx4 per lane). Data written with st_sc +
// vmcnt(0) drain before the flag store => any wg observing flag==target also
// observes the data. Plain launches; all 256 blocks co-resident by construction
// (1 block/CU).
__device__ __forceinline__ void gbar2(unsigned* flags, int wg, unsigned target) {
    asm volatile("s_waitcnt vmcnt(0)" ::: "memory");
    if (threadIdx.x == 0)
        __hip_atomic_store(&flags[wg], target, __ATOMIC_RELAXED, __HIP_MEMORY_SCOPE_AGENT);
    if (threadIdx.x < 64) {
        for (;;) {
            u4_ f = ld4u_sc(flags + (threadIdx.x << 2));
            wait_vm0();
            unsigned m0 = f[0] < f[1] ? f[0] : f[1];
            unsigned m1 = f[2] < f[3] ? f[2] : f[3];
            unsigned mn = m0 < m1 ? m0 : m1;
            if (__all((int)(mn >= target))) break;
            __builtin_amdgcn_s_sleep(1);
        }
    }
    __syncthreads();
}

// ---------------- reverse source indices + barrier-flag init -----------------
__global__ void rev_idx_kernel(const int* __restrict__ src, int* __restrict__ rev,
                               unsigned* __restrict__ bars) {
    int tid = blockIdx.x * blockDim.x + threadIdx.x;
    if (tid < 512) bars[tid] = 0u;
    if (tid < BB * LKK) {
        int b = tid / LKK, t = tid % LKK;
        rev[tid] = src[b * LKK + (LKK - 1 - t)];
    }
}

// ---------------- split-bf16 MFMA NT GEMM ------------------------------------
// C[m,n] = sum_k A[m,k]*Bw[n,k] + bias[n]; A row-major [M,K] (or gathered via
// gidx); Bw row-major [N,K]. M multiple of 128 (always 1024 here). fp32 inputs
// are split into bf16 hi+lo; acc += Ah*Bh + Ah*Bl + Al*Bh (fp32 MFMA accum)
// gives ~fp32 accuracy at ~1/3 the bf16 MFMA rate. act: 0=none, 1=tanh.
typedef __attribute__((ext_vector_type(8))) short bfrag8;   // 8 bf16 (4 VGPR)
typedef __attribute__((ext_vector_type(4))) float facc4;    // 4 fp32 accum

__device__ __forceinline__ unsigned short f2bf(float x) {
    unsigned u = __float_as_uint(x);
    unsigned r = (u + 0x7fffu + ((u >> 16) & 1u)) >> 16;   // round-to-nearest-even
    return (unsigned short)r;
}

#define ASTR 40   // LDS row stride in bf16 elems: 80B rows -> 16B-aligned b128
                  // reads, 16-row column access covers all 32 banks evenly

__global__ __launch_bounds__(256)
void gemm_mfma128(const float* __restrict__ A, const int* __restrict__ gidx, int lda,
                  const float* __restrict__ Bw, int ldb,
                  const float* __restrict__ bias,
                  float* __restrict__ C, int ldc,
                  int N, int K, int act) {
    __shared__ __align__(16) short Ah[128 * ASTR];
    __shared__ __align__(16) short Al[128 * ASTR];
    __shared__ __align__(16) short Bh[128 * ASTR];
    __shared__ __align__(16) short Bl[128 * ASTR];
    int m0 = blockIdx.x * 128;
    int n0 = blockIdx.y * 128;
    int tid = threadIdx.x;
    int lane = tid & 63, w = tid >> 6;
    int wr = w >> 1, wc = w & 1;                  // wave's 64x64 quadrant
    int fr = lane & 15, fg = lane >> 4;           // fragment row/col, k-group

    // staging coords: thread -> (row sr, 16-col half sc)
    int sr = tid >> 1, sc = (tid & 1) << 4;
    long abase = gidx ? (long)gidx[m0 + sr] * lda : (long)(m0 + sr) * lda;
    int gn = n0 + sr;
    bool bval = gn < N;
    long bbase = (long)gn * ldb;

    facc4 acc[4][4] = {};

    for (int k0 = 0; k0 < K; k0 += 32) {
        // ---- stage A tile (fp32 -> bf16 hi/lo) ----
        {
            float v[16];
            if (k0 + sc + 16 <= K) {
                const float* ap = A + abase + k0 + sc;
                float4 t0 = *(const float4*)(ap + 0);
                float4 t1 = *(const float4*)(ap + 4);
                float4 t2 = *(const float4*)(ap + 8);
                float4 t3 = *(const float4*)(ap + 12);
                v[0]=t0.x; v[1]=t0.y; v[2]=t0.z;  v[3]=t0.w;
                v[4]=t1.x; v[5]=t1.y; v[6]=t1.z;  v[7]=t1.w;
                v[8]=t2.x; v[9]=t2.y; v[10]=t2.z; v[11]=t2.w;
                v[12]=t3.x; v[13]=t3.y; v[14]=t3.z; v[15]=t3.w;
            } else {
#pragma unroll
                for (int c = 0; c < 16; c++) {
                    int k = k0 + sc + c;
                    v[c] = (k < K) ? A[abase + k] : 0.f;
                }
            }
            bfrag8 h0, h1, l0, l1;
#pragma unroll
            for (int c = 0; c < 8; c++) {
                unsigned short hb = f2bf(v[c]);
                float hf = __uint_as_float(((unsigned)hb) << 16);
                h0[c] = (short)hb; l0[c] = (short)f2bf(v[c] - hf);
            }
#pragma unroll
            for (int c = 0; c < 8; c++) {
                unsigned short hb = f2bf(v[8 + c]);
                float hf = __uint_as_float(((unsigned)hb) << 16);
                h1[c] = (short)hb; l1[c] = (short)f2bf(v[8 + c] - hf);
            }
            *(bfrag8*)&Ah[sr * ASTR + sc]     = h0;
            *(bfrag8*)&Ah[sr * ASTR + sc + 8] = h1;
            *(bfrag8*)&Al[sr * ASTR + sc]     = l0;
            *(bfrag8*)&Al[sr * ASTR + sc + 8] = l1;
        }
        // ---- stage B tile ----
        {
            float v[16];
            if (bval && (k0 + sc + 16 <= K)) {
                const float* bp = Bw + bbase + k0 + sc;
                float4 t0 = *(const float4*)(bp + 0);
                float4 t1 = *(const float4*)(bp + 4);
                float4 t2 = *(const float4*)(bp + 8);
                float4 t3 = *(const float4*)(bp + 12);
                v[0]=t0.x; v[1]=t0.y; v[2]=t0.z;  v[3]=t0.w;
                v[4]=t1.x; v[5]=t1.y; v[6]=t1.z;  v[7]=t1.w;
                v[8]=t2.x; v[9]=t2.y; v[10]=t2.z; v[11]=t2.w;
                v[12]=t3.x; v[13]=t3.y; v[14]=t3.z; v[15]=t3.w;
            } else {
#pragma unroll
                for (int c = 0; c < 16; c++) {
                    int k = k0 + sc + c;
                    v[c] = (bval && k < K) ? Bw[bbase + k] : 0.f;
                }
            }
            bfrag8 h0, h1, l0, l1;
#pragma unroll
            for (int c = 0; c < 8; c++) {
                unsigned short hb = f2bf(v[c]);
                float hf = __uint_as_float(((unsigned)hb) << 16);
                h0[c] = (short)hb; l0[c] = (short)f2bf(v[c] - hf);
            }
#pragma unroll
            for (int c = 0; c < 8; c++) {
                unsigned short hb = f2bf(v[8 + c]);
                float hf = __uint_as_float(((unsigned)hb) << 16);
                h1[c] = (short)hb; l1[c] = (short)f2bf(v[8 + c] - hf);
            }
            *(bfrag8*)&Bh[sr * ASTR + sc]     = h0;
            *(bfrag8*)&Bh[sr * ASTR + sc + 8] = h1;
            *(bfrag8*)&Bl[sr * ASTR + sc]     = l0;
            *(bfrag8*)&Bl[sr * ASTR + sc + 8] = l1;
        }
        __syncthreads();

        // ---- fragment loads: lane holds 8 contiguous k at row/col = fr ----
        bfrag8 ah[4], al[4], bh[4], bl[4];
#pragma unroll
        for (int i = 0; i < 4; i++) {
            int ar = wr * 64 + i * 16 + fr;
            ah[i] = *(const bfrag8*)&Ah[ar * ASTR + fg * 8];
            al[i] = *(const bfrag8*)&Al[ar * ASTR + fg * 8];
            int br = wc * 64 + i * 16 + fr;
            bh[i] = *(const bfrag8*)&Bh[br * ASTR + fg * 8];
            bl[i] = *(const bfrag8*)&Bl[br * ASTR + fg * 8];
        }
#pragma unroll
        for (int i = 0; i < 4; i++)
#pragma unroll
            for (int j = 0; j < 4; j++) {
                acc[i][j] = __builtin_amdgcn_mfma_f32_16x16x32_bf16(ah[i], bh[j], acc[i][j], 0, 0, 0);
                acc[i][j] = __builtin_amdgcn_mfma_f32_16x16x32_bf16(ah[i], bl[j], acc[i][j], 0, 0, 0);
                acc[i][j] = __builtin_amdgcn_mfma_f32_16x16x32_bf16(al[i], bh[j], acc[i][j], 0, 0, 0);
            }
        __syncthreads();
    }

    // ---- epilogue: C/D layout col=lane&15, row=(lane>>4)*4+q ----
#pragma unroll
    for (int i = 0; i < 4; i++) {
        int row = m0 + wr * 64 + i * 16 + fg * 4;
#pragma unroll
        for (int j = 0; j < 4; j++) {
            int col = n0 + wc * 64 + j * 16 + fr;
            if (col < N) {
                float bz = bias[col];
#pragma unroll
                for (int q = 0; q < 4; q++) {
                    float vv = acc[i][j][q] + bz;
                    if (act == 1) vv = tanhf(vv);
                    C[(long)(row + q) * ldc + col] = vv;
                }
            }
        }
    }
}

// ============ persistent encoder recurrence (fwd+bwd), 256 blocks x 256 =====
// 1 block/CU, 1 wave/SIMD: full 512-VGPR budget keeps wreg in registers.
__global__ __launch_bounds__(256, 1)
void enc_recur(const float* __restrict__ xg_f, const float* __restrict__ xg_b,
               const float* __restrict__ Wf, const float* __restrict__ Wb,
               float* __restrict__ hglob, float* __restrict__ enc_out,
               float* __restrict__ encc, unsigned* __restrict__ flags) {
    __shared__ float hs[HH * 16];       // 32 KB
    __shared__ float gbuf[BB * 17];
    int wg  = blockIdx.x;
    int dir = wg >> 7;
    int j0  = (wg & 127) * 4;
    int tid = threadIdx.x;
    int ks   = tid & 31;
    int tile = tid >> 5;
    int bh   = tile >> 2;
    int nql  = (tile & 3) << 2;
    int gate = nql >> 2;
    int sw   = (ks >> 2) & 3;
    const float* W  = dir ? Wb : Wf;    // [2048][512]
    const float* xg = dir ? xg_b : xg_f;

    float wreg[4][16];
#pragma unroll
    for (int jn = 0; jn < 4; jn++) {
        const float* wrow = W + (long)(gate * HH + j0 + jn) * HH;
#pragma unroll
        for (int j = 0; j < 16; j++) wreg[jn][j] = wrow[ks + 32 * j];
    }

    int ub = tid & 15, ujj = tid >> 4;
    float creg = 0.f;
    float4* hsv = (float4*)hs;

    for (int t = 0; t < LKK; t++) {
        if (t == 0) {
            for (int i = tid; i < HH * 16; i += 256) hs[i] = 0.f;
        } else {
            // h exchange: 8x dwordx4 sc-loads (coalesced, L2-bypassing),
            // single drain, b128 LDS scatter (4 consecutive b share a slot)
            const float* hg = hglob + (long)((dir << 1) | (t & 1)) * (HH * 16);
            f4_ vv[8];
#pragma unroll
            for (int u = 0; u < 8; u++) vv[u] = ld4_sc(hg + tid * 4 + u * 1024);
            wait_vm0();
#pragma unroll
            for (int u = 0; u < 8; u++) {
                int e = tid * 4 + u * 1024;
                int jj = e >> 4, b0 = e & 15;
                *(f4_*)&hs[(jj << 4) + ((((b0 >> 2) ^ ((jj >> 2) & 3))) << 2)] = vv[u];
            }
        }
        float4 xr[8];
        if (ks == 0) {
#pragma unroll
            for (int i = 0; i < 8; i++) {
                const float* xp = xg + (long)((bh * 8 + i) * LKK + t) * G4 + gate * HH + j0;
                xr[i] = *(const float4*)xp;
            }
        }
        __syncthreads();

        float acc[8][4];
#pragma unroll
        for (int i = 0; i < 8; i++)
#pragma unroll
            for (int jn = 0; jn < 4; jn++) acc[i][jn] = 0.f;
#pragma unroll
        for (int j = 0; j < 16; j++) {
            int k = ks + 32 * j;
            float4 h0 = hsv[k * 4 + ((bh * 2 + 0) ^ sw)];
            float4 h1 = hsv[k * 4 + ((bh * 2 + 1) ^ sw)];
#pragma unroll
            for (int jn = 0; jn < 4; jn++) {
                float w = wreg[jn][j];
                acc[0][jn] += h0.x * w; acc[1][jn] += h0.y * w;
                acc[2][jn] += h0.z * w; acc[3][jn] += h0.w * w;
                acc[4][jn] += h1.x * w; acc[5][jn] += h1.y * w;
                acc[6][jn] += h1.z * w; acc[7][jn] += h1.w * w;
            }
        }
#pragma unroll
        for (int i = 0; i < 8; i++)
#pragma unroll
            for (int jn = 0; jn < 4; jn++) {
                float v = acc[i][jn];
                v += __shfl_xor(v, 1, 64);  v += __shfl_xor(v, 2, 64);
                v += __shfl_xor(v, 4, 64);  v += __shfl_xor(v, 8, 64);
                v += __shfl_xor(v, 16, 64);
                acc[i][jn] = v;
            }
        if (ks == 0) {
#pragma unroll
            for (int i = 0; i < 8; i++)
#pragma unroll
                for (int jn = 0; jn < 4; jn++)
                    gbuf[(bh * 8 + i) * 17 + nql + jn] = acc[i][jn] + ((const float*)&xr[i])[jn];
        }
        __syncthreads();

        if (tid < 64) {
            int j = j0 + ujj;
            float gi = gbuf[ub * 17 + 0  + ujj];
            float gf = gbuf[ub * 17 + 4  + ujj];
            float gg = gbuf[ub * 17 + 8  + ujj];
            float go = gbuf[ub * 17 + 12 + ujj];
            float cv = sigmoidf_(gf) * creg + sigmoidf_(gi) * tanhf(gg);
            creg = cv;
            float hv = sigmoidf_(go) * tanhf(cv);
            st_sc(&hglob[(long)((dir << 1) | ((t + 1) & 1)) * (HH * 16) + j * 16 + ub], hv);
            int kpos = dir ? (LKK - 1 - t) : t;
            enc_out[(long)(ub * LKK + kpos) * H2 + dir * HH + j] = hv;
            if (t == LKK - 1) encc[(dir * BB + ub) * HH + j] = creg;
        }
        if (t < LKK - 1) gbar2(flags, wg, (unsigned)(t + 1));
    }
}

// ============ persistent decoder recurrence, 256 blocks x 256 ===============
__global__ __launch_bounds__(256, 1)
void dec_recur(const float* __restrict__ xg_d, const float* __restrict__ Wd,
               const float* __restrict__ enc_out, const float* __restrict__ encc,
               float* __restrict__ hglob, float* __restrict__ Qout,
               unsigned* __restrict__ flags) {
    __shared__ float hs[HH * 16];       // 32 KB (one half of h)
    __shared__ float gbuf[BB * 17];
    int wg  = blockIdx.x;
    int j0  = wg * 4;
    int tid = threadIdx.x;
    int ks   = tid & 31;
    int tile = tid >> 5;
    int bh   = tile >> 2;
    int nql  = (tile & 3) << 2;
    int gate = nql >> 2;
    int sw   = (ks >> 2) & 3;

    float wreg[4][32];
#pragma unroll
    for (int jn = 0; jn < 4; jn++) {
        const float* wrow = Wd + (long)(gate * H2 + j0 + jn) * H2;
#pragma unroll
        for (int j = 0; j < 32; j++) wreg[jn][j] = wrow[ks + 32 * j];
    }

    int ub = tid & 15, ujj = tid >> 4;
    float creg = 0.f;
    if (tid < 64) {
        int j = j0 + ujj;
        creg = ((j & 1) == 0) ? encc[ub * HH + (j >> 1)]
                              : encc[(BB + ub) * HH + (j >> 1)];
    }
    float4* hsv = (float4*)hs;

    for (int t = 0; t < LQQ; t++) {
        float4 xr[8];
        if (ks == 0) {
#pragma unroll
            for (int i = 0; i < 8; i++) {
                const float* xp = xg_d + (long)((bh * 8 + i) * LQQ + t) * G8 + gate * H2 + j0;
                xr[i] = *(const float4*)xp;
            }
        }
        float acc[8][4];
#pragma unroll
        for (int i = 0; i < 8; i++)
#pragma unroll
            for (int jn = 0; jn < 4; jn++) acc[i][jn] = 0.f;

        // FMA over one staged half of h
        auto do_fma = [&](int half) {
#pragma unroll
            for (int jj2 = 0; jj2 < 16; jj2++) {
                int j = half * 16 + jj2;
                int kl = ks + 32 * jj2;
                float4 h0 = hsv[kl * 4 + ((bh * 2 + 0) ^ sw)];
                float4 h1 = hsv[kl * 4 + ((bh * 2 + 1) ^ sw)];
#pragma unroll
                for (int jn = 0; jn < 4; jn++) {
                    float w = wreg[jn][j];
                    acc[0][jn] += h0.x * w; acc[1][jn] += h0.y * w;
                    acc[2][jn] += h0.z * w; acc[3][jn] += h0.w * w;
                    acc[4][jn] += h1.x * w; acc[5][jn] += h1.y * w;
                    acc[6][jn] += h1.z * w; acc[7][jn] += h1.w * w;
                }
            }
        };

        if (t == 0) {
            for (int half = 0; half < 2; half++) {
                for (int e = tid; e < HH * 16; e += 256) {
                    int kl = e >> 4, b = e & 15;
                    int k = half * HH + kl;
                    float hv = ((k & 1) == 0)
                        ? enc_out[(long)(b * LKK + (LKK - 1)) * H2 + (k >> 1)]
                        : enc_out[(long)(b * LKK) * H2 + HH + (k >> 1)];
                    hs[(kl << 4) + ((((b >> 2) ^ ((kl >> 2) & 3))) << 2) + (b & 3)] = hv;
                }
                __syncthreads();
                do_fma(half);
                __syncthreads();
            }
        } else {
            const float* hgA = hglob + (long)(t & 1) * (H2 * 16);
            f4_ vvA[8], vvB[8];
#pragma unroll
            for (int u = 0; u < 8; u++) vvA[u] = ld4_sc(hgA + tid * 4 + u * 1024);
            wait_vm0();
#pragma unroll
            for (int u = 0; u < 8; u++) {
                int e = tid * 4 + u * 1024;
                int kl = e >> 4, b0 = e & 15;
                *(f4_*)&hs[(kl << 4) + ((((b0 >> 2) ^ ((kl >> 2) & 3))) << 2)] = vvA[u];
            }
            // issue half-1 loads now; latency hides under half-0 FMA
#pragma unroll
            for (int u = 0; u < 8; u++) vvB[u] = ld4_sc(hgA + (HH * 16) + tid * 4 + u * 1024);
            __syncthreads();
            do_fma(0);
            __syncthreads();
            wait_vm0();
#pragma unroll
            for (int u = 0; u < 8; u++) {
                int e = tid * 4 + u * 1024;
                int kl = e >> 4, b0 = e & 15;
                *(f4_*)&hs[(kl << 4) + ((((b0 >> 2) ^ ((kl >> 2) & 3))) << 2)] = vvB[u];
            }
            __syncthreads();
            do_fma(1);
            __syncthreads();
        }

#pragma unroll
        for (int i = 0; i < 8; i++)
#pragma unroll
            for (int jn = 0; jn < 4; jn++) {
                float v = acc[i][jn];
                v += __shfl_xor(v, 1, 64);  v += __shfl_xor(v, 2, 64);
                v += __shfl_xor(v, 4, 64);  v += __shfl_xor(v, 8, 64);
                v += __shfl_xor(v, 16, 64);
                acc[i][jn] = v;
            }
        if (ks == 0) {
#pragma unroll
            for (int i = 0; i < 8; i++)
#pragma unroll
                for (int jn = 0; jn < 4; jn++)
                    gbuf[(bh * 8 + i) * 17 + nql + jn] = acc[i][jn] + ((const float*)&xr[i])[jn];
        }
        __syncthreads();

        if (tid < 64) {
            int j = j0 + ujj;
            float gi = gbuf[ub * 17 + 0  + ujj];
            float gf = gbuf[ub * 17 + 4  + ujj];
            float gg = gbuf[ub * 17 + 8  + ujj];
            float go = gbuf[ub * 17 + 12 + ujj];
            float cv = sigmoidf_(gf) * creg + sigmoidf_(gi) * tanhf(gg);
            creg = cv;
            float hv = sigmoidf_(go) * tanhf(cv);
            st_sc(&hglob[(long)((t + 1) & 1) * (H2 * 16) + j * 16 + ub], hv);
            Qout[(long)(ub * LQQ + t) * H2 + j] = hv;
        }
        if (t < LQQ - 1) gbar2(flags, wg, (unsigned)(t + 1));
    }
}

// ---------------- attention + concat[ctx, Q] ---------------------------------
__global__ __launch_bounds__(256)
void attention_kernel(const float* __restrict__ Qm, const float* __restrict__ Km,
                      const float* __restrict__ Vm, const int* __restrict__ source,
                      float* __restrict__ concatBuf) {
    int b = blockIdx.x >> 6;
    int q = blockIdx.x & 63;
    int tid = threadIdx.x;
    __shared__ float qrow[H2];
    __shared__ float part[LKK][4];
    __shared__ float aw[LKK];

    for (int i = tid; i < H2; i += 256) qrow[i] = Qm[(long)(b * LQQ + q) * H2 + i];
    __syncthreads();

    int k = tid >> 2, p = tid & 3;
    {
        const float* krow = Km + (long)(b * LKK + k) * H2 + p * 256;
        const float* qp = qrow + p * 256;
        float s = 0.f;
#pragma unroll 4
        for (int i = 0; i < 256; i++) s += qp[i] * krow[i];
        part[k][p] = s;
    }
    __syncthreads();
    if (tid < 64) {
        float sc = part[tid][0] + part[tid][1] + part[tid][2] + part[tid][3];
        bool masked = (source[b * LKK + tid] == 0);
        float m = masked ? -INFINITY : sc;
#pragma unroll
        for (int o = 32; o >= 1; o >>= 1) m = fmaxf(m, __shfl_xor(m, o, 64));
        float e = masked ? 0.f : expf(sc - m);
        float sum = e;
#pragma unroll
        for (int o = 32; o >= 1; o >>= 1) sum += __shfl_xor(sum, o, 64);
        aw[tid] = e / sum;
    }
    __syncthreads();

    for (int c = tid; c < H2; c += 256) {
        float acc = 0.f;
#pragma unroll 8
        for (int kk = 0; kk < LKK; kk++) acc += aw[kk] * Vm[(long)(b * LKK + kk) * H2 + c];
        long row = (long)(b * LQQ + q) * (2 * H2);
        concatBuf[row + c] = acc;
        concatBuf[row + H2 + c] = qrow[c];
    }
}

// ---------------- host launcher ----------------------------------------------
extern "C" void kernel_launch(void* const* d_in, const int* in_sizes, int n_in,
                              void* d_out, int out_size, void* d_ws, size_t ws_size,
                              hipStream_t stream) {
    const int*   src       = (const int*)  d_in[0];
    const int*   prev      = (const int*)  d_in[1];
    const float* emb       = (const float*)d_in[2];
    const float* enc_f_Wih = (const float*)d_in[3];
    const float* enc_f_Whh = (const float*)d_in[4];
    const float* enc_f_b   = (const float*)d_in[5];
    const float* enc_b_Wih = (const float*)d_in[6];
    const float* enc_b_Whh = (const float*)d_in[7];
    const float* enc_b_b   = (const float*)d_in[8];
    const float* dec_Wih   = (const float*)d_in[9];
    const float* dec_Whh   = (const float*)d_in[10];
    const float* dec_b     = (const float*)d_in[11];
    const float* k_W  = (const float*)d_in[12];
    const float* k_b  = (const float*)d_in[13];
    const float* v_W  = (const float*)d_in[14];
    const float* v_b  = (const float*)d_in[15];
    const float* fc1_W = (const float*)d_in[16];
    const float* fc1_b = (const float*)d_in[17];
    const float* fc2_W = (const float*)d_in[18];
    const float* fc2_b = (const float*)d_in[19];
    float* out = (float*)d_out;

    // workspace layout (floats) — kept identical to prior rounds
    float* p = (float*)d_ws;
    float* xg_f    = p; p += (long)BB * LKK * G4;
    float* xg_b    = p; p += (long)BB * LKK * G4;
    float* xg_d    = p; p += (long)BB * LQQ * G8;
    float* enc_out = p; p += (long)BB * LKK * H2;
    float* encc    = p; p += 2L * BB * HH;
    float* hg_enc  = p; p += 2L * 2 * HH * 16;
    float* hg_dec  = p; p += 2L * H2 * 16;
    float* Qbuf    = p; p += (long)BB * LQQ * H2;
    float* Kbuf    = p; p += (long)BB * LKK * H2;
    float* Vbuf    = p; p += (long)BB * LKK * H2;
    float* concatB = p; p += (long)BB * LQQ * 2 * H2;
    float* fc1out  = p; p += (long)BB * LQQ * H2;
    int*   rev     = (int*)p; p += (BB * LKK);
    unsigned* bars = (unsigned*)p; p += 512;     // flags: enc [0:256), dec [256:512)

    // 1) reversed source indices + barrier-flag zero
    rev_idx_kernel<<<4, 256, 0, stream>>>(src, rev, bars);

    // 2) xg precomputes (gathered-embedding GEMMs), M = 1024
    gemm_mfma128<<<dim3(8, G4 / 128), 256, 0, stream>>>(emb, src, DD, enc_f_Wih, DD,
                                                        enc_f_b, xg_f, G4, G4, DD, 0);
    gemm_mfma128<<<dim3(8, G4 / 128), 256, 0, stream>>>(emb, rev, DD, enc_b_Wih, DD,
                                                        enc_b_b, xg_b, G4, G4, DD, 0);
    gemm_mfma128<<<dim3(8, G8 / 128), 256, 0, stream>>>(emb, prev, DD, dec_Wih, DD,
                                                        dec_b, xg_d, G8, G8, DD, 0);

    // 3) encoder recurrence: persistent kernel, 256 blocks x 256 threads
    enc_recur<<<dim3(256), dim3(256), 0, stream>>>(xg_f, xg_b, enc_f_Whh, enc_b_Whh,
                                                   hg_enc, enc_out, encc, bars);

    // 4) K/V projections
    gemm_mfma128<<<dim3(8, 8), 256, 0, stream>>>(enc_out, nullptr, H2, k_W, H2,
                                                 k_b, Kbuf, H2, H2, H2, 0);
    gemm_mfma128<<<dim3(8, 8), 256, 0, stream>>>(enc_out, nullptr, H2, v_W, H2,
                                                 v_b, Vbuf, H2, H2, H2, 0);

    // 5) decoder recurrence: persistent kernel, 256 blocks x 256 threads
    dec_recur<<<dim3(256), dim3(256), 0, stream>>>(xg_d, dec_Whh, enc_out, encc,
                                                   hg_dec, Qbuf, bars + 256);

    // 6) attention -> concat[ctx, Q]
    attention_kernel<<<BB * LQQ, 256, 0, stream>>>(Qbuf, Kbuf, Vbuf, src, concatB);

    // 7) fc1 with tanh
    gemm_mfma128<<<dim3(8, 8), 256, 0, stream>>>(concatB, nullptr, 2 * H2, fc1_W, 2 * H2,
                                                 fc1_b, fc1out, H2, H2, 2 * H2, 1);

    // 8) fc2 -> output [1024, 10000]
    gemm_mfma128<<<dim3(8, (VV + 127) / 128), 256, 0, stream>>>(fc1out, nullptr, H2, fc2_W, H2,
                                                                fc2_b, out, VV, VV, H2, 0);
}

// Round 6
// 1606.538 us; speedup vs baseline: 2.9411x; 1.1628x over previous
//
#include <hip/hip_runtime.h>
#include <cmath>

// Problem constants
#define BB   16
#define LKK  64
#define LQQ  64
#define DD   300
#define HH   512
#define H2   1024
#define G4   2048
#define G8   4096
#define VV   10000

__device__ __forceinline__ float sigmoidf_(float x) { return 1.f / (1.f + expf(-x)); }

typedef __attribute__((ext_vector_type(4))) float    f4_;
typedef __attribute__((ext_vector_type(4))) unsigned u4_;

// ---- agent-scope (cross-XCD coherent) scalar store ----
__device__ __forceinline__ void st_sc(float* p, float v) {
    __hip_atomic_store(p, v, __ATOMIC_RELAXED, __HIP_MEMORY_SCOPE_AGENT);
}

// ---- wide agent-coherent loads: global_load_dwordx4 sc0 sc1 (cache-bypassing,
// coalesced). Caller must wait_vm0() before use.
__device__ __forceinline__ f4_ ld4_sc(const float* p) {
    f4_ r;
    asm volatile("global_load_dwordx4 %0, %1, off sc0 sc1" : "=v"(r) : "v"(p));
    return r;
}
__device__ __forceinline__ u4_ ld4u_sc(const unsigned* p) {
    u4_ r;
    asm volatile("global_load_dwordx4 %0, %1, off sc0 sc1" : "=v"(r) : "v"(p));
    return r;
}
__device__ __forceinline__ void wait_vm0() {
    asm volatile("s_waitcnt vmcnt(0)" ::: "memory");
    __builtin_amdgcn_sched_barrier(0);
}

// ---- contention-free grid barrier (256 flags), plain launch, 1 block/CU ----
__device__ __forceinline__ void gbar2(unsigned* flags, int wg, unsigned target) {
    asm volatile("s_waitcnt vmcnt(0)" ::: "memory");
    if (threadIdx.x == 0)
        __hip_atomic_store(&flags[wg], target, __ATOMIC_RELAXED, __HIP_MEMORY_SCOPE_AGENT);
    if (threadIdx.x < 64) {
        for (;;) {
            u4_ f = ld4u_sc(flags + (threadIdx.x << 2));
            wait_vm0();
            unsigned m0 = f[0] < f[1] ? f[0] : f[1];
            unsigned m1 = f[2] < f[3] ? f[2] : f[3];
            unsigned mn = m0 < m1 ? m0 : m1;
            if (__all((int)(mn >= target))) break;
            __builtin_amdgcn_s_sleep(1);
        }
    }
    __syncthreads();
}

// ---------------- reverse source indices + barrier-flag init -----------------
__global__ void rev_idx_kernel(const int* __restrict__ src, int* __restrict__ rev,
                               unsigned* __restrict__ bars) {
    int tid = blockIdx.x * blockDim.x + threadIdx.x;
    if (tid < 512) bars[tid] = 0u;
    if (tid < BB * LKK) {
        int b = tid / LKK, t = tid % LKK;
        rev[tid] = src[b * LKK + (LKK - 1 - t)];
    }
}

// ---------------- split-bf16 MFMA NT GEMM core -------------------------------
// C[m,n] = sum_k A[m,k]*Bw[n,k] + bias[n]; split-bf16 hi/lo 3-product MFMA.
typedef __attribute__((ext_vector_type(8))) short bfrag8;   // 8 bf16 (4 VGPR)
typedef __attribute__((ext_vector_type(4))) float facc4;    // 4 fp32 accum

__device__ __forceinline__ unsigned short f2bf(float x) {
    unsigned u = __float_as_uint(x);
    unsigned r = (u + 0x7fffu + ((u >> 16) & 1u)) >> 16;   // round-to-nearest-even
    return (unsigned short)r;
}

#define ASTR 40   // LDS row stride in bf16 elems: 80B rows -> 16B-aligned b128

__device__ __forceinline__ void gemm_core(
        short* __restrict__ Ah, short* __restrict__ Al,
        short* __restrict__ Bh, short* __restrict__ Bl,
        const float* __restrict__ A, const int* __restrict__ gidx, int lda,
        const float* __restrict__ Bw, int ldb,
        const float* __restrict__ bias,
        float* __restrict__ C, int ldc,
        int N, int K, int act, int m0, int n0) {
    int tid = threadIdx.x;
    int lane = tid & 63, w = tid >> 6;
    int wr = w >> 1, wc = w & 1;                  // wave's 64x64 quadrant
    int fr = lane & 15, fg = lane >> 4;           // fragment row/col, k-group

    int sr = tid >> 1, sc = (tid & 1) << 4;
    long abase = gidx ? (long)gidx[m0 + sr] * lda : (long)(m0 + sr) * lda;
    int gn = n0 + sr;
    bool bval = gn < N;
    long bbase = (long)gn * ldb;

    facc4 acc[4][4] = {};

    for (int k0 = 0; k0 < K; k0 += 32) {
        // ---- stage A tile (fp32 -> bf16 hi/lo) ----
        {
            float v[16];
            if (k0 + sc + 16 <= K) {
                const float* ap = A + abase + k0 + sc;
                float4 t0 = *(const float4*)(ap + 0);
                float4 t1 = *(const float4*)(ap + 4);
                float4 t2 = *(const float4*)(ap + 8);
                float4 t3 = *(const float4*)(ap + 12);
                v[0]=t0.x; v[1]=t0.y; v[2]=t0.z;  v[3]=t0.w;
                v[4]=t1.x; v[5]=t1.y; v[6]=t1.z;  v[7]=t1.w;
                v[8]=t2.x; v[9]=t2.y; v[10]=t2.z; v[11]=t2.w;
                v[12]=t3.x; v[13]=t3.y; v[14]=t3.z; v[15]=t3.w;
            } else {
#pragma unroll
                for (int c = 0; c < 16; c++) {
                    int k = k0 + sc + c;
                    v[c] = (k < K) ? A[abase + k] : 0.f;
                }
            }
            bfrag8 h0, h1, l0, l1;
#pragma unroll
            for (int c = 0; c < 8; c++) {
                unsigned short hb = f2bf(v[c]);
                float hf = __uint_as_float(((unsigned)hb) << 16);
                h0[c] = (short)hb; l0[c] = (short)f2bf(v[c] - hf);
            }
#pragma unroll
            for (int c = 0; c < 8; c++) {
                unsigned short hb = f2bf(v[8 + c]);
                float hf = __uint_as_float(((unsigned)hb) << 16);
                h1[c] = (short)hb; l1[c] = (short)f2bf(v[8 + c] - hf);
            }
            *(bfrag8*)&Ah[sr * ASTR + sc]     = h0;
            *(bfrag8*)&Ah[sr * ASTR + sc + 8] = h1;
            *(bfrag8*)&Al[sr * ASTR + sc]     = l0;
            *(bfrag8*)&Al[sr * ASTR + sc + 8] = l1;
        }
        // ---- stage B tile ----
        {
            float v[16];
            if (bval && (k0 + sc + 16 <= K)) {
                const float* bp = Bw + bbase + k0 + sc;
                float4 t0 = *(const float4*)(bp + 0);
                float4 t1 = *(const float4*)(bp + 4);
                float4 t2 = *(const float4*)(bp + 8);
                float4 t3 = *(const float4*)(bp + 12);
                v[0]=t0.x; v[1]=t0.y; v[2]=t0.z;  v[3]=t0.w;
                v[4]=t1.x; v[5]=t1.y; v[6]=t1.z;  v[7]=t1.w;
                v[8]=t2.x; v[9]=t2.y; v[10]=t2.z; v[11]=t2.w;
                v[12]=t3.x; v[13]=t3.y; v[14]=t3.z; v[15]=t3.w;
            } else {
#pragma unroll
                for (int c = 0; c < 16; c++) {
                    int k = k0 + sc + c;
                    v[c] = (bval && k < K) ? Bw[bbase + k] : 0.f;
                }
            }
            bfrag8 h0, h1, l0, l1;
#pragma unroll
            for (int c = 0; c < 8; c++) {
                unsigned short hb = f2bf(v[c]);
                float hf = __uint_as_float(((unsigned)hb) << 16);
                h0[c] = (short)hb; l0[c] = (short)f2bf(v[c] - hf);
            }
#pragma unroll
            for (int c = 0; c < 8; c++) {
                unsigned short hb = f2bf(v[8 + c]);
                float hf = __uint_as_float(((unsigned)hb) << 16);
                h1[c] = (short)hb; l1[c] = (short)f2bf(v[8 + c] - hf);
            }
            *(bfrag8*)&Bh[sr * ASTR + sc]     = h0;
            *(bfrag8*)&Bh[sr * ASTR + sc + 8] = h1;
            *(bfrag8*)&Bl[sr * ASTR + sc]     = l0;
            *(bfrag8*)&Bl[sr * ASTR + sc + 8] = l1;
        }
        __syncthreads();

        bfrag8 ah[4], al[4], bh[4], bl[4];
#pragma unroll
        for (int i = 0; i < 4; i++) {
            int ar = wr * 64 + i * 16 + fr;
            ah[i] = *(const bfrag8*)&Ah[ar * ASTR + fg * 8];
            al[i] = *(const bfrag8*)&Al[ar * ASTR + fg * 8];
            int br = wc * 64 + i * 16 + fr;
            bh[i] = *(const bfrag8*)&Bh[br * ASTR + fg * 8];
            bl[i] = *(const bfrag8*)&Bl[br * ASTR + fg * 8];
        }
#pragma unroll
        for (int i = 0; i < 4; i++)
#pragma unroll
            for (int j = 0; j < 4; j++) {
                acc[i][j] = __builtin_amdgcn_mfma_f32_16x16x32_bf16(ah[i], bh[j], acc[i][j], 0, 0, 0);
                acc[i][j] = __builtin_amdgcn_mfma_f32_16x16x32_bf16(ah[i], bl[j], acc[i][j], 0, 0, 0);
                acc[i][j] = __builtin_amdgcn_mfma_f32_16x16x32_bf16(al[i], bh[j], acc[i][j], 0, 0, 0);
            }
        __syncthreads();
    }

#pragma unroll
    for (int i = 0; i < 4; i++) {
        int row = m0 + wr * 64 + i * 16 + fg * 4;
#pragma unroll
        for (int j = 0; j < 4; j++) {
            int col = n0 + wc * 64 + j * 16 + fr;
            if (col < N) {
                float bz = bias[col];
#pragma unroll
                for (int q = 0; q < 4; q++) {
                    float vv = acc[i][j][q] + bz;
                    if (act == 1) vv = tanhf(vv);
                    C[(long)(row + q) * ldc + col] = vv;
                }
            }
        }
    }
}

__global__ __launch_bounds__(256)
void gemm_mfma128(const float* __restrict__ A, const int* __restrict__ gidx, int lda,
                  const float* __restrict__ Bw, int ldb,
                  const float* __restrict__ bias,
                  float* __restrict__ C, int ldc,
                  int N, int K, int act) {
    __shared__ __align__(16) short Ah[128 * ASTR];
    __shared__ __align__(16) short Al[128 * ASTR];
    __shared__ __align__(16) short Bh[128 * ASTR];
    __shared__ __align__(16) short Bl[128 * ASTR];
    gemm_core(Ah, Al, Bh, Bl, A, gidx, lda, Bw, ldb, bias, C, ldc, N, K, act,
              blockIdx.x * 128, blockIdx.y * 128);
}

// K and V projections fused into one 128-block dispatch (2x concurrency)
__global__ __launch_bounds__(256)
void gemm_kv(const float* __restrict__ enc_out,
             const float* __restrict__ kW, const float* __restrict__ kb,
             const float* __restrict__ vW, const float* __restrict__ vb,
             float* __restrict__ Kbuf, float* __restrict__ Vbuf) {
    __shared__ __align__(16) short Ah[128 * ASTR];
    __shared__ __align__(16) short Al[128 * ASTR];
    __shared__ __align__(16) short Bh[128 * ASTR];
    __shared__ __align__(16) short Bl[128 * ASTR];
    int ny = blockIdx.y;
    if (ny < 8)
        gemm_core(Ah, Al, Bh, Bl, enc_out, nullptr, H2, kW, H2, kb, Kbuf, H2,
                  H2, H2, 0, blockIdx.x * 128, ny * 128);
    else
        gemm_core(Ah, Al, Bh, Bl, enc_out, nullptr, H2, vW, H2, vb, Vbuf, H2,
                  H2, H2, 0, blockIdx.x * 128, (ny - 8) * 128);
}

// three xg precompute GEMMs fused into one 512-block dispatch
__global__ __launch_bounds__(256)
void gemm_xg(const float* __restrict__ emb,
             const int* __restrict__ src, const int* __restrict__ rev,
             const int* __restrict__ prev,
             const float* __restrict__ Wf, const float* __restrict__ bf,
             const float* __restrict__ Wb, const float* __restrict__ bb,
             const float* __restrict__ Wd, const float* __restrict__ bd,
             float* __restrict__ xf, float* __restrict__ xb,
             float* __restrict__ xd) {
    __shared__ __align__(16) short Ah[128 * ASTR];
    __shared__ __align__(16) short Al[128 * ASTR];
    __shared__ __align__(16) short Bh[128 * ASTR];
    __shared__ __align__(16) short Bl[128 * ASTR];
    int ny = blockIdx.y;
    if (ny < 16)
        gemm_core(Ah, Al, Bh, Bl, emb, src, DD, Wf, DD, bf, xf, G4,
                  G4, DD, 0, blockIdx.x * 128, ny * 128);
    else if (ny < 32)
        gemm_core(Ah, Al, Bh, Bl, emb, rev, DD, Wb, DD, bb, xb, G4,
                  G4, DD, 0, blockIdx.x * 128, (ny - 16) * 128);
    else
        gemm_core(Ah, Al, Bh, Bl, emb, prev, DD, Wd, DD, bd, xd, G8,
                  G8, DD, 0, blockIdx.x * 128, (ny - 32) * 128);
}

// ============ persistent encoder recurrence (fwd+bwd), 256 blocks x 256 =====
// Reduction: LDS transpose (stride-33, conflict-free) instead of shuffle
// butterfly; all 256 threads compute one gate value each (nonlinearity /4).
__global__ __launch_bounds__(256, 1)
void enc_recur(const float* __restrict__ xg_f, const float* __restrict__ xg_b,
               const float* __restrict__ Wf, const float* __restrict__ Wb,
               float* __restrict__ hglob, float* __restrict__ enc_out,
               float* __restrict__ encc, unsigned* __restrict__ flags) {
    __shared__ float hs[HH * 16];          // 32 KB
    __shared__ float red[256 * 33];        // 33 KB transpose-reduce scratch
    __shared__ float g256[256];
    int wg  = blockIdx.x;
    int dir = wg >> 7;
    int j0  = (wg & 127) * 4;
    int tid = threadIdx.x;
    int ks   = tid & 31;
    int tile = tid >> 5;
    int bh   = tile >> 2;
    int gate = tile & 3;
    int sw   = (ks >> 2) & 3;
    const float* W  = dir ? Wb : Wf;    // [2048][512]
    const float* xg = dir ? xg_b : xg_f;

    float wreg[4][16];
#pragma unroll
    for (int jn = 0; jn < 4; jn++) {
        const float* wrow = W + (long)(gate * HH + j0 + jn) * HH;
#pragma unroll
        for (int j = 0; j < 16; j++) wreg[jn][j] = wrow[ks + 32 * j];
    }

    int ub = tid & 15, ujj = tid >> 4;
    int xb = tid >> 4, xgate = (tid >> 2) & 3, xjn = tid & 3;
    float creg = 0.f;
    float4* hsv = (float4*)hs;

    for (int t = 0; t < LKK; t++) {
        if (t == 0) {
            for (int i = tid; i < HH * 16; i += 256) hs[i] = 0.f;
        } else {
            const float* hg = hglob + (long)((dir << 1) | (t & 1)) * (HH * 16);
            f4_ vv[8];
#pragma unroll
            for (int u = 0; u < 8; u++) vv[u] = ld4_sc(hg + tid * 4 + u * 1024);
            wait_vm0();
#pragma unroll
            for (int u = 0; u < 8; u++) {
                int e = tid * 4 + u * 1024;
                int jj = e >> 4, b0 = e & 15;
                *(f4_*)&hs[(jj << 4) + ((((b0 >> 2) ^ ((jj >> 2) & 3))) << 2)] = vv[u];
            }
        }
        // per-thread xg gate value (thread t <-> (b=xb, gate=xgate, jn=xjn))
        float xval = xg[(long)(xb * LKK + t) * G4 + xgate * HH + j0 + xjn];
        __syncthreads();

        float acc[8][4];
#pragma unroll
        for (int i = 0; i < 8; i++)
#pragma unroll
            for (int jn = 0; jn < 4; jn++) acc[i][jn] = 0.f;
#pragma unroll
        for (int j = 0; j < 16; j++) {
            int k = ks + 32 * j;
            float4 h0 = hsv[k * 4 + ((bh * 2 + 0) ^ sw)];
            float4 h1 = hsv[k * 4 + ((bh * 2 + 1) ^ sw)];
#pragma unroll
            for (int jn = 0; jn < 4; jn++) {
                float w = wreg[jn][j];
                acc[0][jn] += h0.x * w; acc[1][jn] += h0.y * w;
                acc[2][jn] += h0.z * w; acc[3][jn] += h0.w * w;
                acc[4][jn] += h1.x * w; acc[5][jn] += h1.y * w;
                acc[6][jn] += h1.z * w; acc[7][jn] += h1.w * w;
            }
        }
        // transpose-reduce: row r = (b*16 + gate*4 + jn), col = ks
#pragma unroll
        for (int i = 0; i < 8; i++)
#pragma unroll
            for (int jn = 0; jn < 4; jn++)
                red[((bh * 8 + i) * 16 + gate * 4 + jn) * 33 + ks] = acc[i][jn];
        __syncthreads();
        {
            const float* row = red + tid * 33;
            float s0 = 0.f, s1 = 0.f, s2 = 0.f, s3 = 0.f;
#pragma unroll
            for (int u = 0; u < 8; u++) {
                s0 += row[u * 4 + 0]; s1 += row[u * 4 + 1];
                s2 += row[u * 4 + 2]; s3 += row[u * 4 + 3];
            }
            g256[tid] = ((s0 + s1) + (s2 + s3)) + xval;
        }
        __syncthreads();

        if (tid < 64) {
            int j = j0 + ujj;
            float gi = g256[ub * 16 + 0  + ujj];
            float gf = g256[ub * 16 + 4  + ujj];
            float gg = g256[ub * 16 + 8  + ujj];
            float go = g256[ub * 16 + 12 + ujj];
            float cv = sigmoidf_(gf) * creg + sigmoidf_(gi) * tanhf(gg);
            creg = cv;
            float hv = sigmoidf_(go) * tanhf(cv);
            st_sc(&hglob[(long)((dir << 1) | ((t + 1) & 1)) * (HH * 16) + j * 16 + ub], hv);
            int kpos = dir ? (LKK - 1 - t) : t;
            enc_out[(long)(ub * LKK + kpos) * H2 + dir * HH + j] = hv;
            if (t == LKK - 1) encc[(dir * BB + ub) * HH + j] = creg;
        }
        if (t < LKK - 1) gbar2(flags, wg, (unsigned)(t + 1));
    }
}

// ============ persistent decoder recurrence, 256 blocks x 256 ===============
__global__ __launch_bounds__(256, 1)
void dec_recur(const float* __restrict__ xg_d, const float* __restrict__ Wd,
               const float* __restrict__ enc_out, const float* __restrict__ encc,
               float* __restrict__ hglob, float* __restrict__ Qout,
               unsigned* __restrict__ flags) {
    __shared__ float hs[HH * 16];          // 32 KB (one half of h)
    __shared__ float red[256 * 33];        // 33 KB
    __shared__ float g256[256];
    int wg  = blockIdx.x;
    int j0  = wg * 4;
    int tid = threadIdx.x;
    int ks   = tid & 31;
    int tile = tid >> 5;
    int bh   = tile >> 2;
    int gate = tile & 3;
    int sw   = (ks >> 2) & 3;

    float wreg[4][32];
#pragma unroll
    for (int jn = 0; jn < 4; jn++) {
        const float* wrow = Wd + (long)(gate * H2 + j0 + jn) * H2;
#pragma unroll
        for (int j = 0; j < 32; j++) wreg[jn][j] = wrow[ks + 32 * j];
    }

    int ub = tid & 15, ujj = tid >> 4;
    int xb = tid >> 4, xgate = (tid >> 2) & 3, xjn = tid & 3;
    float creg = 0.f;
    if (tid < 64) {
        int j = j0 + ujj;
        creg = ((j & 1) == 0) ? encc[ub * HH + (j >> 1)]
                              : encc[(BB + ub) * HH + (j >> 1)];
    }
    float4* hsv = (float4*)hs;

    for (int t = 0; t < LQQ; t++) {
        float xval = xg_d[(long)(xb * LQQ + t) * G8 + xgate * H2 + j0 + xjn];
        float acc[8][4];
#pragma unroll
        for (int i = 0; i < 8; i++)
#pragma unroll
            for (int jn = 0; jn < 4; jn++) acc[i][jn] = 0.f;

        auto do_fma = [&](int half) {
#pragma unroll
            for (int jj2 = 0; jj2 < 16; jj2++) {
                int j = half * 16 + jj2;
                int kl = ks + 32 * jj2;
                float4 h0 = hsv[kl * 4 + ((bh * 2 + 0) ^ sw)];
                float4 h1 = hsv[kl * 4 + ((bh * 2 + 1) ^ sw)];
#pragma unroll
                for (int jn = 0; jn < 4; jn++) {
                    float w = wreg[jn][j];
                    acc[0][jn] += h0.x * w; acc[1][jn] += h0.y * w;
                    acc[2][jn] += h0.z * w; acc[3][jn] += h0.w * w;
                    acc[4][jn] += h1.x * w; acc[5][jn] += h1.y * w;
                    acc[6][jn] += h1.z * w; acc[7][jn] += h1.w * w;
                }
            }
        };

        if (t == 0) {
            for (int half = 0; half < 2; half++) {
                for (int e = tid; e < HH * 16; e += 256) {
                    int kl = e >> 4, b = e & 15;
                    int k = half * HH + kl;
                    float hv = ((k & 1) == 0)
                        ? enc_out[(long)(b * LKK + (LKK - 1)) * H2 + (k >> 1)]
                        : enc_out[(long)(b * LKK) * H2 + HH + (k >> 1)];
                    hs[(kl << 4) + ((((b >> 2) ^ ((kl >> 2) & 3))) << 2) + (b & 3)] = hv;
                }
                __syncthreads();
                do_fma(half);
                __syncthreads();
            }
        } else {
            const float* hgA = hglob + (long)(t & 1) * (H2 * 16);
            f4_ vvA[8], vvB[8];
#pragma unroll
            for (int u = 0; u < 8; u++) vvA[u] = ld4_sc(hgA + tid * 4 + u * 1024);
            wait_vm0();
#pragma unroll
            for (int u = 0; u < 8; u++) {
                int e = tid * 4 + u * 1024;
                int kl = e >> 4, b0 = e & 15;
                *(f4_*)&hs[(kl << 4) + ((((b0 >> 2) ^ ((kl >> 2) & 3))) << 2)] = vvA[u];
            }
            // issue half-1 loads now; latency hides under half-0 FMA
#pragma unroll
            for (int u = 0; u < 8; u++) vvB[u] = ld4_sc(hgA + (HH * 16) + tid * 4 + u * 1024);
            __syncthreads();
            do_fma(0);
            __syncthreads();
            wait_vm0();
#pragma unroll
            for (int u = 0; u < 8; u++) {
                int e = tid * 4 + u * 1024;
                int kl = e >> 4, b0 = e & 15;
                *(f4_*)&hs[(kl << 4) + ((((b0 >> 2) ^ ((kl >> 2) & 3))) << 2)] = vvB[u];
            }
            __syncthreads();
            do_fma(1);
        }

        // transpose-reduce
#pragma unroll
        for (int i = 0; i < 8; i++)
#pragma unroll
            for (int jn = 0; jn < 4; jn++)
                red[((bh * 8 + i) * 16 + gate * 4 + jn) * 33 + ks] = acc[i][jn];
        __syncthreads();
        {
            const float* row = red + tid * 33;
            float s0 = 0.f, s1 = 0.f, s2 = 0.f, s3 = 0.f;
#pragma unroll
            for (int u = 0; u < 8; u++) {
                s0 += row[u * 4 + 0]; s1 += row[u * 4 + 1];
                s2 += row[u * 4 + 2]; s3 += row[u * 4 + 3];
            }
            g256[tid] = ((s0 + s1) + (s2 + s3)) + xval;
        }
        __syncthreads();

        if (tid < 64) {
            int j = j0 + ujj;
            float gi = g256[ub * 16 + 0  + ujj];
            float gf = g256[ub * 16 + 4  + ujj];
            float gg = g256[ub * 16 + 8  + ujj];
            float go = g256[ub * 16 + 12 + ujj];
            float cv = sigmoidf_(gf) * creg + sigmoidf_(gi) * tanhf(gg);
            creg = cv;
            float hv = sigmoidf_(go) * tanhf(cv);
            st_sc(&hglob[(long)((t + 1) & 1) * (H2 * 16) + j * 16 + ub], hv);
            Qout[(long)(ub * LQQ + t) * H2 + j] = hv;
        }
        if (t < LQQ - 1) gbar2(flags, wg, (unsigned)(t + 1));
    }
}

// ---------------- attention + concat[ctx, Q] ---------------------------------
__global__ __launch_bounds__(256)
void attention_kernel(const float* __restrict__ Qm, const float* __restrict__ Km,
                      const float* __restrict__ Vm, const int* __restrict__ source,
                      float* __restrict__ concatBuf) {
    int b = blockIdx.x >> 6;
    int q = blockIdx.x & 63;
    int tid = threadIdx.x;
    __shared__ float qrow[H2];
    __shared__ float part[LKK][4];
    __shared__ float aw[LKK];

    for (int i = tid; i < H2; i += 256) qrow[i] = Qm[(long)(b * LQQ + q) * H2 + i];
    __syncthreads();

    int k = tid >> 2, p = tid & 3;
    {
        const float* krow = Km + (long)(b * LKK + k) * H2 + p * 256;
        const float* qp = qrow + p * 256;
        float s = 0.f;
#pragma unroll 4
        for (int i = 0; i < 256; i++) s += qp[i] * krow[i];
        part[k][p] = s;
    }
    __syncthreads();
    if (tid < 64) {
        float sc = part[tid][0] + part[tid][1] + part[tid][2] + part[tid][3];
        bool masked = (source[b * LKK + tid] == 0);
        float m = masked ? -INFINITY : sc;
#pragma unroll
        for (int o = 32; o >= 1; o >>= 1) m = fmaxf(m, __shfl_xor(m, o, 64));
        float e = masked ? 0.f : expf(sc - m);
        float sum = e;
#pragma unroll
        for (int o = 32; o >= 1; o >>= 1) sum += __shfl_xor(sum, o, 64);
        aw[tid] = e / sum;
    }
    __syncthreads();

    for (int c = tid; c < H2; c += 256) {
        float acc = 0.f;
#pragma unroll 8
        for (int kk = 0; kk < LKK; kk++) acc += aw[kk] * Vm[(long)(b * LKK + kk) * H2 + c];
        long row = (long)(b * LQQ + q) * (2 * H2);
        concatBuf[row + c] = acc;
        concatBuf[row + H2 + c] = qrow[c];
    }
}

// ---------------- host launcher ----------------------------------------------
extern "C" void kernel_launch(void* const* d_in, const int* in_sizes, int n_in,
                              void* d_out, int out_size, void* d_ws, size_t ws_size,
                              hipStream_t stream) {
    const int*   src       = (const int*)  d_in[0];
    const int*   prev      = (const int*)  d_in[1];
    const float* emb       = (const float*)d_in[2];
    const float* enc_f_Wih = (const float*)d_in[3];
    const float* enc_f_Whh = (const float*)d_in[4];
    const float* enc_f_b   = (const float*)d_in[5];
    const float* enc_b_Wih = (const float*)d_in[6];
    const float* enc_b_Whh = (const float*)d_in[7];
    const float* enc_b_b   = (const float*)d_in[8];
    const float* dec_Wih   = (const float*)d_in[9];
    const float* dec_Whh   = (const float*)d_in[10];
    const float* dec_b     = (const float*)d_in[11];
    const float* k_W  = (const float*)d_in[12];
    const float* k_b  = (const float*)d_in[13];
    const float* v_W  = (const float*)d_in[14];
    const float* v_b  = (const float*)d_in[15];
    const float* fc1_W = (const float*)d_in[16];
    const float* fc1_b = (const float*)d_in[17];
    const float* fc2_W = (const float*)d_in[18];
    const float* fc2_b = (const float*)d_in[19];
    float* out = (float*)d_out;

    // workspace layout (floats)
    float* p = (float*)d_ws;
    float* xg_f    = p; p += (long)BB * LKK * G4;
    float* xg_b    = p; p += (long)BB * LKK * G4;
    float* xg_d    = p; p += (long)BB * LQQ * G8;
    float* enc_out = p; p += (long)BB * LKK * H2;
    float* encc    = p; p += 2L * BB * HH;
    float* hg_enc  = p; p += 2L * 2 * HH * 16;
    float* hg_dec  = p; p += 2L * H2 * 16;
    float* Qbuf    = p; p += (long)BB * LQQ * H2;
    float* Kbuf    = p; p += (long)BB * LKK * H2;
    float* Vbuf    = p; p += (long)BB * LKK * H2;
    float* concatB = p; p += (long)BB * LQQ * 2 * H2;
    float* fc1out  = p; p += (long)BB * LQQ * H2;
    int*   rev     = (int*)p; p += (BB * LKK);
    unsigned* bars = (unsigned*)p; p += 512;     // flags: enc [0:256), dec [256:512)

    // 1) reversed source indices + barrier-flag zero
    rev_idx_kernel<<<4, 256, 0, stream>>>(src, rev, bars);

    // 2) xg precomputes, fused into one 512-block dispatch
    gemm_xg<<<dim3(8, 64), 256, 0, stream>>>(emb, src, rev, prev,
                                             enc_f_Wih, enc_f_b,
                                             enc_b_Wih, enc_b_b,
                                             dec_Wih, dec_b,
                                             xg_f, xg_b, xg_d);

    // 3) encoder recurrence: persistent, 256 blocks x 256 threads
    enc_recur<<<dim3(256), dim3(256), 0, stream>>>(xg_f, xg_b, enc_f_Whh, enc_b_Whh,
                                                   hg_enc, enc_out, encc, bars);

    // 4) K/V projections fused (128 blocks)
    gemm_kv<<<dim3(8, 16), 256, 0, stream>>>(enc_out, k_W, k_b, v_W, v_b, Kbuf, Vbuf);

    // 5) decoder recurrence: persistent, 256 blocks x 256 threads
    dec_recur<<<dim3(256), dim3(256), 0, stream>>>(xg_d, dec_Whh, enc_out, encc,
                                                   hg_dec, Qbuf, bars + 256);

    // 6) attention -> concat[ctx, Q]
    attention_kernel<<<BB * LQQ, 256, 0, stream>>>(Qbuf, Kbuf, Vbuf, src, concatB);

    // 7) fc1 with tanh
    gemm_mfma128<<<dim3(8, 8), 256, 0, stream>>>(concatB, nullptr, 2 * H2, fc1_W, 2 * H2,
                                                 fc1_b, fc1out, H2, H2, 2 * H2, 1);

    // 8) fc2 -> output [1024, 10000]
    gemm_mfma128<<<dim3(8, (VV + 127) / 128), 256, 0, stream>>>(fc1out, nullptr, H2, fc2_W, H2,
                                                                fc2_b, out, VV, VV, H2, 0);
}

// Round 7
// 1592.297 us; speedup vs baseline: 2.9674x; 1.0089x over previous
//
#include <hip/hip_runtime.h>
#include <cmath>

// Problem constants
#define BB   16
#define LKK  64
#define LQQ  64
#define DD   300
#define HH   512
#define H2   1024
#define G4   2048
#define G8   4096
#define VV   10000

__device__ __forceinline__ float sigmoidf_(float x) { return 1.f / (1.f + expf(-x)); }

typedef __attribute__((ext_vector_type(4))) float    f4_;
typedef __attribute__((ext_vector_type(4))) unsigned u4_;

// ---- agent-scope (cross-XCD coherent) scalar store ----
__device__ __forceinline__ void st_sc(float* p, float v) {
    __hip_atomic_store(p, v, __ATOMIC_RELAXED, __HIP_MEMORY_SCOPE_AGENT);
}

// ---- wide agent-coherent loads: global_load_dwordx4 sc0 sc1 (cache-bypassing,
// coalesced). Caller must wait (vmcnt) + sched_barrier before using results.
__device__ __forceinline__ f4_ ld4_sc(const float* p) {
    f4_ r;
    asm volatile("global_load_dwordx4 %0, %1, off sc0 sc1" : "=v"(r) : "v"(p));
    return r;
}
__device__ __forceinline__ u4_ ld4u_sc(const unsigned* p) {
    u4_ r;
    asm volatile("global_load_dwordx4 %0, %1, off sc0 sc1" : "=v"(r) : "v"(p));
    return r;
}
__device__ __forceinline__ void wait_vm0() {
    asm volatile("s_waitcnt vmcnt(0)" ::: "memory");
    __builtin_amdgcn_sched_barrier(0);
}

// ---- contention-free grid barrier (256 flags), plain launch, 1 block/CU ----
__device__ __forceinline__ void gbar2(unsigned* flags, int wg, unsigned target) {
    asm volatile("s_waitcnt vmcnt(0)" ::: "memory");
    if (threadIdx.x == 0)
        __hip_atomic_store(&flags[wg], target, __ATOMIC_RELAXED, __HIP_MEMORY_SCOPE_AGENT);
    if (threadIdx.x < 64) {
        for (;;) {
            u4_ f = ld4u_sc(flags + (threadIdx.x << 2));
            wait_vm0();
            unsigned m0 = f[0] < f[1] ? f[0] : f[1];
            unsigned m1 = f[2] < f[3] ? f[2] : f[3];
            unsigned mn = m0 < m1 ? m0 : m1;
            if (__all((int)(mn >= target))) break;
            __builtin_amdgcn_s_sleep(1);
        }
    }
    __syncthreads();
}

// ---------------- reverse source indices + barrier-flag init -----------------
__global__ void rev_idx_kernel(const int* __restrict__ src, int* __restrict__ rev,
                               unsigned* __restrict__ bars) {
    int tid = blockIdx.x * blockDim.x + threadIdx.x;
    if (tid < 512) bars[tid] = 0u;
    if (tid < BB * LKK) {
        int b = tid / LKK, t = tid % LKK;
        rev[tid] = src[b * LKK + (LKK - 1 - t)];
    }
}

// ---------------- split-bf16 MFMA NT GEMM core -------------------------------
typedef __attribute__((ext_vector_type(8))) short bfrag8;   // 8 bf16 (4 VGPR)
typedef __attribute__((ext_vector_type(4))) float facc4;    // 4 fp32 accum

__device__ __forceinline__ unsigned short f2bf(float x) {
    unsigned u = __float_as_uint(x);
    unsigned r = (u + 0x7fffu + ((u >> 16) & 1u)) >> 16;   // round-to-nearest-even
    return (unsigned short)r;
}

#define ASTR 40   // LDS row stride in bf16 elems: 80B rows -> 16B-aligned b128

__device__ __forceinline__ void gemm_core(
        short* __restrict__ Ah, short* __restrict__ Al,
        short* __restrict__ Bh, short* __restrict__ Bl,
        const float* __restrict__ A, const int* __restrict__ gidx, int lda,
        const float* __restrict__ Bw, int ldb,
        const float* __restrict__ bias,
        float* __restrict__ C, int ldc,
        int N, int K, int act, int m0, int n0) {
    int tid = threadIdx.x;
    int lane = tid & 63, w = tid >> 6;
    int wr = w >> 1, wc = w & 1;                  // wave's 64x64 quadrant
    int fr = lane & 15, fg = lane >> 4;           // fragment row/col, k-group

    int sr = tid >> 1, sc = (tid & 1) << 4;
    long abase = gidx ? (long)gidx[m0 + sr] * lda : (long)(m0 + sr) * lda;
    int gn = n0 + sr;
    bool bval = gn < N;
    long bbase = (long)gn * ldb;

    facc4 acc[4][4] = {};

    for (int k0 = 0; k0 < K; k0 += 32) {
        // ---- stage A tile (fp32 -> bf16 hi/lo) ----
        {
            float v[16];
            if (k0 + sc + 16 <= K) {
                const float* ap = A + abase + k0 + sc;
                float4 t0 = *(const float4*)(ap + 0);
                float4 t1 = *(const float4*)(ap + 4);
                float4 t2 = *(const float4*)(ap + 8);
                float4 t3 = *(const float4*)(ap + 12);
                v[0]=t0.x; v[1]=t0.y; v[2]=t0.z;  v[3]=t0.w;
                v[4]=t1.x; v[5]=t1.y; v[6]=t1.z;  v[7]=t1.w;
                v[8]=t2.x; v[9]=t2.y; v[10]=t2.z; v[11]=t2.w;
                v[12]=t3.x; v[13]=t3.y; v[14]=t3.z; v[15]=t3.w;
            } else {
#pragma unroll
                for (int c = 0; c < 16; c++) {
                    int k = k0 + sc + c;
                    v[c] = (k < K) ? A[abase + k] : 0.f;
                }
            }
            bfrag8 h0, h1, l0, l1;
#pragma unroll
            for (int c = 0; c < 8; c++) {
                unsigned short hb = f2bf(v[c]);
                float hf = __uint_as_float(((unsigned)hb) << 16);
                h0[c] = (short)hb; l0[c] = (short)f2bf(v[c] - hf);
            }
#pragma unroll
            for (int c = 0; c < 8; c++) {
                unsigned short hb = f2bf(v[8 + c]);
                float hf = __uint_as_float(((unsigned)hb) << 16);
                h1[c] = (short)hb; l1[c] = (short)f2bf(v[8 + c] - hf);
            }
            *(bfrag8*)&Ah[sr * ASTR + sc]     = h0;
            *(bfrag8*)&Ah[sr * ASTR + sc + 8] = h1;
            *(bfrag8*)&Al[sr * ASTR + sc]     = l0;
            *(bfrag8*)&Al[sr * ASTR + sc + 8] = l1;
        }
        // ---- stage B tile ----
        {
            float v[16];
            if (bval && (k0 + sc + 16 <= K)) {
                const float* bp = Bw + bbase + k0 + sc;
                float4 t0 = *(const float4*)(bp + 0);
                float4 t1 = *(const float4*)(bp + 4);
                float4 t2 = *(const float4*)(bp + 8);
                float4 t3 = *(const float4*)(bp + 12);
                v[0]=t0.x; v[1]=t0.y; v[2]=t0.z;  v[3]=t0.w;
                v[4]=t1.x; v[5]=t1.y; v[6]=t1.z;  v[7]=t1.w;
                v[8]=t2.x; v[9]=t2.y; v[10]=t2.z; v[11]=t2.w;
                v[12]=t3.x; v[13]=t3.y; v[14]=t3.z; v[15]=t3.w;
            } else {
#pragma unroll
                for (int c = 0; c < 16; c++) {
                    int k = k0 + sc + c;
                    v[c] = (bval && k < K) ? Bw[bbase + k] : 0.f;
                }
            }
            bfrag8 h0, h1, l0, l1;
#pragma unroll
            for (int c = 0; c < 8; c++) {
                unsigned short hb = f2bf(v[c]);
                float hf = __uint_as_float(((unsigned)hb) << 16);
                h0[c] = (short)hb; l0[c] = (short)f2bf(v[c] - hf);
            }
#pragma unroll
            for (int c = 0; c < 8; c++) {
                unsigned short hb = f2bf(v[8 + c]);
                float hf = __uint_as_float(((unsigned)hb) << 16);
                h1[c] = (short)hb; l1[c] = (short)f2bf(v[8 + c] - hf);
            }
            *(bfrag8*)&Bh[sr * ASTR + sc]     = h0;
            *(bfrag8*)&Bh[sr * ASTR + sc + 8] = h1;
            *(bfrag8*)&Bl[sr * ASTR + sc]     = l0;
            *(bfrag8*)&Bl[sr * ASTR + sc + 8] = l1;
        }
        __syncthreads();

        bfrag8 ah[4], al[4], bh[4], bl[4];
#pragma unroll
        for (int i = 0; i < 4; i++) {
            int ar = wr * 64 + i * 16 + fr;
            ah[i] = *(const bfrag8*)&Ah[ar * ASTR + fg * 8];
            al[i] = *(const bfrag8*)&Al[ar * ASTR + fg * 8];
            int br = wc * 64 + i * 16 + fr;
            bh[i] = *(const bfrag8*)&Bh[br * ASTR + fg * 8];
            bl[i] = *(const bfrag8*)&Bl[br * ASTR + fg * 8];
        }
#pragma unroll
        for (int i = 0; i < 4; i++)
#pragma unroll
            for (int j = 0; j < 4; j++) {
                acc[i][j] = __builtin_amdgcn_mfma_f32_16x16x32_bf16(ah[i], bh[j], acc[i][j], 0, 0, 0);
                acc[i][j] = __builtin_amdgcn_mfma_f32_16x16x32_bf16(ah[i], bl[j], acc[i][j], 0, 0, 0);
                acc[i][j] = __builtin_amdgcn_mfma_f32_16x16x32_bf16(al[i], bh[j], acc[i][j], 0, 0, 0);
            }
        __syncthreads();
    }

#pragma unroll
    for (int i = 0; i < 4; i++) {
        int row = m0 + wr * 64 + i * 16 + fg * 4;
#pragma unroll
        for (int j = 0; j < 4; j++) {
            int col = n0 + wc * 64 + j * 16 + fr;
            if (col < N) {
                float bz = bias[col];
#pragma unroll
                for (int q = 0; q < 4; q++) {
                    float vv = acc[i][j][q] + bz;
                    if (act == 1) vv = tanhf(vv);
                    C[(long)(row + q) * ldc + col] = vv;
                }
            }
        }
    }
}

__global__ __launch_bounds__(256)
void gemm_mfma128(const float* __restrict__ A, const int* __restrict__ gidx, int lda,
                  const float* __restrict__ Bw, int ldb,
                  const float* __restrict__ bias,
                  float* __restrict__ C, int ldc,
                  int N, int K, int act) {
    __shared__ __align__(16) short Ah[128 * ASTR];
    __shared__ __align__(16) short Al[128 * ASTR];
    __shared__ __align__(16) short Bh[128 * ASTR];
    __shared__ __align__(16) short Bl[128 * ASTR];
    gemm_core(Ah, Al, Bh, Bl, A, gidx, lda, Bw, ldb, bias, C, ldc, N, K, act,
              blockIdx.x * 128, blockIdx.y * 128);
}

// K and V projections fused into one 128-block dispatch (2x concurrency)
__global__ __launch_bounds__(256)
void gemm_kv(const float* __restrict__ enc_out,
             const float* __restrict__ kW, const float* __restrict__ kb,
             const float* __restrict__ vW, const float* __restrict__ vb,
             float* __restrict__ Kbuf, float* __restrict__ Vbuf) {
    __shared__ __align__(16) short Ah[128 * ASTR];
    __shared__ __align__(16) short Al[128 * ASTR];
    __shared__ __align__(16) short Bh[128 * ASTR];
    __shared__ __align__(16) short Bl[128 * ASTR];
    int ny = blockIdx.y;
    if (ny < 8)
        gemm_core(Ah, Al, Bh, Bl, enc_out, nullptr, H2, kW, H2, kb, Kbuf, H2,
                  H2, H2, 0, blockIdx.x * 128, ny * 128);
    else
        gemm_core(Ah, Al, Bh, Bl, enc_out, nullptr, H2, vW, H2, vb, Vbuf, H2,
                  H2, H2, 0, blockIdx.x * 128, (ny - 8) * 128);
}

// three xg precompute GEMMs fused into one 512-block dispatch
__global__ __launch_bounds__(256)
void gemm_xg(const float* __restrict__ emb,
             const int* __restrict__ src, const int* __restrict__ rev,
             const int* __restrict__ prev,
             const float* __restrict__ Wf, const float* __restrict__ bf,
             const float* __restrict__ Wb, const float* __restrict__ bb,
             const float* __restrict__ Wd, const float* __restrict__ bd,
             float* __restrict__ xf, float* __restrict__ xb,
             float* __restrict__ xd) {
    __shared__ __align__(16) short Ah[128 * ASTR];
    __shared__ __align__(16) short Al[128 * ASTR];
    __shared__ __align__(16) short Bh[128 * ASTR];
    __shared__ __align__(16) short Bl[128 * ASTR];
    int ny = blockIdx.y;
    if (ny < 16)
        gemm_core(Ah, Al, Bh, Bl, emb, src, DD, Wf, DD, bf, xf, G4,
                  G4, DD, 0, blockIdx.x * 128, ny * 128);
    else if (ny < 32)
        gemm_core(Ah, Al, Bh, Bl, emb, rev, DD, Wb, DD, bb, xb, G4,
                  G4, DD, 0, blockIdx.x * 128, (ny - 16) * 128);
    else
        gemm_core(Ah, Al, Bh, Bl, emb, prev, DD, Wd, DD, bd, xd, G8,
                  G8, DD, 0, blockIdx.x * 128, (ny - 32) * 128);
}

// ============ persistent encoder recurrence (fwd+bwd), 256 blocks x 256 =====
// Producer critical path = gates + 1 sc-store + flag. Output (enc_out) stores
// are deferred to wave 1 AFTER the barrier (their acks drain a step later).
// h-load split: vmcnt(4) after 8 issued -> rows<256 scatter+FMA j<8 overlap
// the in-flight rows>=256 (safe: u4..u7 always issue after u3).
__global__ __launch_bounds__(256, 1)
void enc_recur(const float* __restrict__ xg_f, const float* __restrict__ xg_b,
               const float* __restrict__ Wf, const float* __restrict__ Wb,
               float* __restrict__ hglob, float* __restrict__ enc_out,
               float* __restrict__ encc, unsigned* __restrict__ flags) {
    __shared__ float hs[HH * 16];          // 32 KB
    __shared__ float red[256 * 33];        // 33 KB transpose-reduce scratch
    __shared__ float g256[256];
    __shared__ float hout[64];
    int wg  = blockIdx.x;
    int dir = wg >> 7;
    int j0  = (wg & 127) * 4;
    int tid = threadIdx.x;
    int ks   = tid & 31;
    int tile = tid >> 5;
    int bh   = tile >> 2;
    int gate = tile & 3;
    int sw   = (ks >> 2) & 3;
    const float* W  = dir ? Wb : Wf;    // [2048][512]
    const float* xg = dir ? xg_b : xg_f;

    float wreg[4][16];
#pragma unroll
    for (int jn = 0; jn < 4; jn++) {
        const float* wrow = W + (long)(gate * HH + j0 + jn) * HH;
#pragma unroll
        for (int j = 0; j < 16; j++) wreg[jn][j] = wrow[ks + 32 * j];
    }

    int ub = tid & 15, ujj = tid >> 4;
    int xb = tid >> 4, xgate = (tid >> 2) & 3, xjn = tid & 3;
    float creg = 0.f;
    float4* hsv = (float4*)hs;

    for (int t = 0; t < LKK; t++) {
        float acc[8][4];
#pragma unroll
        for (int i = 0; i < 8; i++)
#pragma unroll
            for (int jn = 0; jn < 4; jn++) acc[i][jn] = 0.f;

        auto do_fma = [&](int jlo, int jhi) {
#pragma unroll
            for (int j = jlo; j < jhi; j++) {
                int k = ks + 32 * j;
                float4 h0 = hsv[k * 4 + ((bh * 2 + 0) ^ sw)];
                float4 h1 = hsv[k * 4 + ((bh * 2 + 1) ^ sw)];
#pragma unroll
                for (int jn = 0; jn < 4; jn++) {
                    float w = wreg[jn][j];
                    acc[0][jn] += h0.x * w; acc[1][jn] += h0.y * w;
                    acc[2][jn] += h0.z * w; acc[3][jn] += h0.w * w;
                    acc[4][jn] += h1.x * w; acc[5][jn] += h1.y * w;
                    acc[6][jn] += h1.z * w; acc[7][jn] += h1.w * w;
                }
            }
        };

        float xval = xg[(long)(xb * LKK + t) * G4 + xgate * HH + j0 + xjn];

        if (t == 0) {
            for (int i = tid; i < HH * 16; i += 256) hs[i] = 0.f;
            __syncthreads();
            do_fma(0, 16);
        } else {
            const float* hg = hglob + (long)((dir << 1) | (t & 1)) * (HH * 16);
            f4_ vv[8];
#pragma unroll
            for (int u = 0; u < 8; u++) vv[u] = ld4_sc(hg + tid * 4 + u * 1024);
            asm volatile("s_waitcnt vmcnt(4)" ::: "memory");
            __builtin_amdgcn_sched_barrier(0);
#pragma unroll
            for (int u = 0; u < 4; u++) {
                int e = tid * 4 + u * 1024;
                int jj = e >> 4, b0 = e & 15;
                *(f4_*)&hs[(jj << 4) + ((((b0 >> 2) ^ ((jj >> 2) & 3))) << 2)] = vv[u];
            }
            __syncthreads();
            do_fma(0, 8);          // rows < 256; rows >= 256 still in flight
            wait_vm0();
#pragma unroll
            for (int u = 4; u < 8; u++) {
                int e = tid * 4 + u * 1024;
                int jj = e >> 4, b0 = e & 15;
                *(f4_*)&hs[(jj << 4) + ((((b0 >> 2) ^ ((jj >> 2) & 3))) << 2)] = vv[u];
            }
            __syncthreads();
            do_fma(8, 16);
        }

        // transpose-reduce: row r = (b*16 + gate*4 + jn), col = ks
#pragma unroll
        for (int i = 0; i < 8; i++)
#pragma unroll
            for (int jn = 0; jn < 4; jn++)
                red[((bh * 8 + i) * 16 + gate * 4 + jn) * 33 + ks] = acc[i][jn];
        __syncthreads();
        {
            const float* row = red + tid * 33;
            float s0 = 0.f, s1 = 0.f, s2 = 0.f, s3 = 0.f;
#pragma unroll
            for (int u = 0; u < 8; u++) {
                s0 += row[u * 4 + 0]; s1 += row[u * 4 + 1];
                s2 += row[u * 4 + 2]; s3 += row[u * 4 + 3];
            }
            g256[tid] = ((s0 + s1) + (s2 + s3)) + xval;
        }
        __syncthreads();

        if (tid < 64) {
            int j = j0 + ujj;
            float gi = g256[ub * 16 + 0  + ujj];
            float gf = g256[ub * 16 + 4  + ujj];
            float gg = g256[ub * 16 + 8  + ujj];
            float go = g256[ub * 16 + 12 + ujj];
            float cv = sigmoidf_(gf) * creg + sigmoidf_(gi) * tanhf(gg);
            creg = cv;
            float hv = sigmoidf_(go) * tanhf(cv);
            st_sc(&hglob[(long)((dir << 1) | ((t + 1) & 1)) * (HH * 16) + j * 16 + ub], hv);
            hout[tid] = hv;
            if (t == LKK - 1) encc[(dir * BB + ub) * HH + j] = creg;
        }
        if (t < LKK - 1) gbar2(flags, wg, (unsigned)(t + 1));
        else __syncthreads();
        // deferred output store by wave 1 (drains at next barrier entry)
        if (tid >= 64 && tid < 128) {
            int lt = tid - 64;
            int j = j0 + (lt >> 4);
            int kpos = dir ? (LKK - 1 - t) : t;
            enc_out[(long)((lt & 15) * LKK + kpos) * H2 + dir * HH + j] = hout[lt];
        }
    }
}

// ============ persistent decoder recurrence, 256 blocks x 256 ===============
__global__ __launch_bounds__(256, 1)
void dec_recur(const float* __restrict__ xg_d, const float* __restrict__ Wd,
               const float* __restrict__ enc_out, const float* __restrict__ encc,
               float* __restrict__ hglob, float* __restrict__ Qout,
               unsigned* __restrict__ flags) {
    __shared__ float hs[HH * 16];          // 32 KB (one half of h)
    __shared__ float red[256 * 33];        // 33 KB
    __shared__ float g256[256];
    __shared__ float hout[64];
    int wg  = blockIdx.x;
    int j0  = wg * 4;
    int tid = threadIdx.x;
    int ks   = tid & 31;
    int tile = tid >> 5;
    int bh   = tile >> 2;
    int gate = tile & 3;
    int sw   = (ks >> 2) & 3;

    float wreg[4][32];
#pragma unroll
    for (int jn = 0; jn < 4; jn++) {
        const float* wrow = Wd + (long)(gate * H2 + j0 + jn) * H2;
#pragma unroll
        for (int j = 0; j < 32; j++) wreg[jn][j] = wrow[ks + 32 * j];
    }

    int ub = tid & 15, ujj = tid >> 4;
    int xb = tid >> 4, xgate = (tid >> 2) & 3, xjn = tid & 3;
    float creg = 0.f;
    if (tid < 64) {
        int j = j0 + ujj;
        creg = ((j & 1) == 0) ? encc[ub * HH + (j >> 1)]
                              : encc[(BB + ub) * HH + (j >> 1)];
    }
    float4* hsv = (float4*)hs;

    for (int t = 0; t < LQQ; t++) {
        float xval = xg_d[(long)(xb * LQQ + t) * G8 + xgate * H2 + j0 + xjn];
        float acc[8][4];
#pragma unroll
        for (int i = 0; i < 8; i++)
#pragma unroll
            for (int jn = 0; jn < 4; jn++) acc[i][jn] = 0.f;

        auto do_fma = [&](int half) {
#pragma unroll
            for (int jj2 = 0; jj2 < 16; jj2++) {
                int j = half * 16 + jj2;
                int kl = ks + 32 * jj2;
                float4 h0 = hsv[kl * 4 + ((bh * 2 + 0) ^ sw)];
                float4 h1 = hsv[kl * 4 + ((bh * 2 + 1) ^ sw)];
#pragma unroll
                for (int jn = 0; jn < 4; jn++) {
                    float w = wreg[jn][j];
                    acc[0][jn] += h0.x * w; acc[1][jn] += h0.y * w;
                    acc[2][jn] += h0.z * w; acc[3][jn] += h0.w * w;
                    acc[4][jn] += h1.x * w; acc[5][jn] += h1.y * w;
                    acc[6][jn] += h1.z * w; acc[7][jn] += h1.w * w;
                }
            }
        };

        if (t == 0) {
            for (int half = 0; half < 2; half++) {
                for (int e = tid; e < HH * 16; e += 256) {
                    int kl = e >> 4, b = e & 15;
                    int k = half * HH + kl;
                    float hv = ((k & 1) == 0)
                        ? enc_out[(long)(b * LKK + (LKK - 1)) * H2 + (k >> 1)]
                        : enc_out[(long)(b * LKK) * H2 + HH + (k >> 1)];
                    hs[(kl << 4) + ((((b >> 2) ^ ((kl >> 2) & 3))) << 2) + (b & 3)] = hv;
                }
                __syncthreads();
                do_fma(half);
                __syncthreads();
            }
        } else {
            const float* hgA = hglob + (long)(t & 1) * (H2 * 16);
            f4_ vvA[8], vvB[8];
#pragma unroll
            for (int u = 0; u < 8; u++) vvA[u] = ld4_sc(hgA + tid * 4 + u * 1024);
#pragma unroll
            for (int u = 0; u < 8; u++) vvB[u] = ld4_sc(hgA + (HH * 16) + tid * 4 + u * 1024);
            asm volatile("s_waitcnt vmcnt(8)" ::: "memory");   // A done, B in flight
            __builtin_amdgcn_sched_barrier(0);
#pragma unroll
            for (int u = 0; u < 8; u++) {
                int e = tid * 4 + u * 1024;
                int kl = e >> 4, b0 = e & 15;
                *(f4_*)&hs[(kl << 4) + ((((b0 >> 2) ^ ((kl >> 2) & 3))) << 2)] = vvA[u];
            }
            __syncthreads();
            do_fma(0);
            __syncthreads();
            wait_vm0();
#pragma unroll
            for (int u = 0; u < 8; u++) {
                int e = tid * 4 + u * 1024;
                int kl = e >> 4, b0 = e & 15;
                *(f4_*)&hs[(kl << 4) + ((((b0 >> 2) ^ ((kl >> 2) & 3))) << 2)] = vvB[u];
            }
            __syncthreads();
            do_fma(1);
        }

        // transpose-reduce
#pragma unroll
        for (int i = 0; i < 8; i++)
#pragma unroll
            for (int jn = 0; jn < 4; jn++)
                red[((bh * 8 + i) * 16 + gate * 4 + jn) * 33 + ks] = acc[i][jn];
        __syncthreads();
        {
            const float* row = red + tid * 33;
            float s0 = 0.f, s1 = 0.f, s2 = 0.f, s3 = 0.f;
#pragma unroll
            for (int u = 0; u < 8; u++) {
                s0 += row[u * 4 + 0]; s1 += row[u * 4 + 1];
                s2 += row[u * 4 + 2]; s3 += row[u * 4 + 3];
            }
            g256[tid] = ((s0 + s1) + (s2 + s3)) + xval;
        }
        __syncthreads();

        if (tid < 64) {
            int j = j0 + ujj;
            float gi = g256[ub * 16 + 0  + ujj];
            float gf = g256[ub * 16 + 4  + ujj];
            float gg = g256[ub * 16 + 8  + ujj];
            float go = g256[ub * 16 + 12 + ujj];
            float cv = sigmoidf_(gf) * creg + sigmoidf_(gi) * tanhf(gg);
            creg = cv;
            float hv = sigmoidf_(go) * tanhf(cv);
            st_sc(&hglob[(long)((t + 1) & 1) * (H2 * 16) + j * 16 + ub], hv);
            hout[tid] = hv;
        }
        if (t < LQQ - 1) gbar2(flags, wg, (unsigned)(t + 1));
        else __syncthreads();
        // deferred Qout store by wave 1 (drains at next barrier entry)
        if (tid >= 64 && tid < 128) {
            int lt = tid - 64;
            int j = j0 + (lt >> 4);
            Qout[(long)((lt & 15) * LQQ + t) * H2 + j] = hout[lt];
        }
    }
}

// ---------------- attention + concat[ctx, Q] ---------------------------------
__global__ __launch_bounds__(256)
void attention_kernel(const float* __restrict__ Qm, const float* __restrict__ Km,
                      const float* __restrict__ Vm, const int* __restrict__ source,
                      float* __restrict__ concatBuf) {
    int b = blockIdx.x >> 6;
    int q = blockIdx.x & 63;
    int tid = threadIdx.x;
    __shared__ float qrow[H2];
    __shared__ float part[LKK][4];
    __shared__ float aw[LKK];

    for (int i = tid; i < H2; i += 256) qrow[i] = Qm[(long)(b * LQQ + q) * H2 + i];
    __syncthreads();

    int k = tid >> 2, p = tid & 3;
    {
        const float* krow = Km + (long)(b * LKK + k) * H2 + p * 256;
        const float* qp = qrow + p * 256;
        float s = 0.f;
#pragma unroll 4
        for (int i = 0; i < 256; i++) s += qp[i] * krow[i];
        part[k][p] = s;
    }
    __syncthreads();
    if (tid < 64) {
        float sc = part[tid][0] + part[tid][1] + part[tid][2] + part[tid][3];
        bool masked = (source[b * LKK + tid] == 0);
        float m = masked ? -INFINITY : sc;
#pragma unroll
        for (int o = 32; o >= 1; o >>= 1) m = fmaxf(m, __shfl_xor(m, o, 64));
        float e = masked ? 0.f : expf(sc - m);
        float sum = e;
#pragma unroll
        for (int o = 32; o >= 1; o >>= 1) sum += __shfl_xor(sum, o, 64);
        aw[tid] = e / sum;
    }
    __syncthreads();

    for (int c = tid; c < H2; c += 256) {
        float acc = 0.f;
#pragma unroll 8
        for (int kk = 0; kk < LKK; kk++) acc += aw[kk] * Vm[(long)(b * LKK + kk) * H2 + c];
        long row = (long)(b * LQQ + q) * (2 * H2);
        concatBuf[row + c] = acc;
        concatBuf[row + H2 + c] = qrow[c];
    }
}

// ---------------- host launcher ----------------------------------------------
extern "C" void kernel_launch(void* const* d_in, const int* in_sizes, int n_in,
                              void* d_out, int out_size, void* d_ws, size_t ws_size,
                              hipStream_t stream) {
    const int*   src       = (const int*)  d_in[0];
    const int*   prev      = (const int*)  d_in[1];
    const float* emb       = (const float*)d_in[2];
    const float* enc_f_Wih = (const float*)d_in[3];
    const float* enc_f_Whh = (const float*)d_in[4];
    const float* enc_f_b   = (const float*)d_in[5];
    const float* enc_b_Wih = (const float*)d_in[6];
    const float* enc_b_Whh = (const float*)d_in[7];
    const float* enc_b_b   = (const float*)d_in[8];
    const float* dec_Wih   = (const float*)d_in[9];
    const float* dec_Whh   = (const float*)d_in[10];
    const float* dec_b     = (const float*)d_in[11];
    const float* k_W  = (const float*)d_in[12];
    const float* k_b  = (const float*)d_in[13];
    const float* v_W  = (const float*)d_in[14];
    const float* v_b  = (const float*)d_in[15];
    const float* fc1_W = (const float*)d_in[16];
    const float* fc1_b = (const float*)d_in[17];
    const float* fc2_W = (const float*)d_in[18];
    const float* fc2_b = (const float*)d_in[19];
    float* out = (float*)d_out;

    // workspace layout (floats)
    float* p = (float*)d_ws;
    float* xg_f    = p; p += (long)BB * LKK * G4;
    float* xg_b    = p; p += (long)BB * LKK * G4;
    float* xg_d    = p; p += (long)BB * LQQ * G8;
    float* enc_out = p; p += (long)BB * LKK * H2;
    float* encc    = p; p += 2L * BB * HH;
    float* hg_enc  = p; p += 2L * 2 * HH * 16;
    float* hg_dec  = p; p += 2L * H2 * 16;
    float* Qbuf    = p; p += (long)BB * LQQ * H2;
    float* Kbuf    = p; p += (long)BB * LKK * H2;
    float* Vbuf    = p; p += (long)BB * LKK * H2;
    float* concatB = p; p += (long)BB * LQQ * 2 * H2;
    float* fc1out  = p; p += (long)BB * LQQ * H2;
    int*   rev     = (int*)p; p += (BB * LKK);
    unsigned* bars = (unsigned*)p; p += 512;     // flags: enc [0:256), dec [256:512)

    // 1) reversed source indices + barrier-flag zero
    rev_idx_kernel<<<4, 256, 0, stream>>>(src, rev, bars);

    // 2) xg precomputes, fused into one 512-block dispatch
    gemm_xg<<<dim3(8, 64), 256, 0, stream>>>(emb, src, rev, prev,
                                             enc_f_Wih, enc_f_b,
                                             enc_b_Wih, enc_b_b,
                                             dec_Wih, dec_b,
                                             xg_f, xg_b, xg_d);

    // 3) encoder recurrence: persistent, 256 blocks x 256 threads
    enc_recur<<<dim3(256), dim3(256), 0, stream>>>(xg_f, xg_b, enc_f_Whh, enc_b_Whh,
                                                   hg_enc, enc_out, encc, bars);

    // 4) K/V projections fused (128 blocks)
    gemm_kv<<<dim3(8, 16), 256, 0, stream>>>(enc_out, k_W, k_b, v_W, v_b, Kbuf, Vbuf);

    // 5) decoder recurrence: persistent, 256 blocks x 256 threads
    dec_recur<<<dim3(256), dim3(256), 0, stream>>>(xg_d, dec_Whh, enc_out, encc,
                                                   hg_dec, Qbuf, bars + 256);

    // 6) attention -> concat[ctx, Q]
    attention_kernel<<<BB * LQQ, 256, 0, stream>>>(Qbuf, Kbuf, Vbuf, src, concatB);

    // 7) fc1 with tanh
    gemm_mfma128<<<dim3(8, 8), 256, 0, stream>>>(concatB, nullptr, 2 * H2, fc1_W, 2 * H2,
                                                 fc1_b, fc1out, H2, H2, 2 * H2, 1);

    // 8) fc2 -> output [1024, 10000]
    gemm_mfma128<<<dim3(8, (VV + 127) / 128), 256, 0, stream>>>(fc1out, nullptr, H2, fc2_W, H2,
                                                                fc2_b, out, VV, VV, H2, 0);
}

// Round 8
// 1527.893 us; speedup vs baseline: 3.0924x; 1.0422x over previous
//
#include <hip/hip_runtime.h>
#include <cmath>

// Problem constants
#define BB   16
#define LKK  64
#define LQQ  64
#define DD   300
#define HH   512
#define H2   1024
#define G4   2048
#define G8   4096
#define VV   10000

__device__ __forceinline__ float sigmoidf_(float x) { return 1.f / (1.f + expf(-x)); }

typedef __attribute__((ext_vector_type(4))) float    f4_;
typedef __attribute__((ext_vector_type(4))) unsigned u4_;
typedef __attribute__((ext_vector_type(2))) unsigned u2_;

// ---- agent-scope (cross-XCD coherent) scalar store ----
__device__ __forceinline__ void st_sc(float* p, float v) {
    __hip_atomic_store(p, v, __ATOMIC_RELAXED, __HIP_MEMORY_SCOPE_AGENT);
}

// ---- wide agent-coherent loads: global_load_dwordx4/x2 sc0 sc1 (cache-
// bypassing, coalesced). Caller must wait (vmcnt) + sched_barrier before use.
__device__ __forceinline__ f4_ ld4_sc(const float* p) {
    f4_ r;
    asm volatile("global_load_dwordx4 %0, %1, off sc0 sc1" : "=v"(r) : "v"(p));
    return r;
}
__device__ __forceinline__ u4_ ld4u_sc(const unsigned* p) {
    u4_ r;
    asm volatile("global_load_dwordx4 %0, %1, off sc0 sc1" : "=v"(r) : "v"(p));
    return r;
}
__device__ __forceinline__ u2_ ld2u_sc(const unsigned* p) {
    u2_ r;
    asm volatile("global_load_dwordx2 %0, %1, off sc0 sc1" : "=v"(r) : "v"(p));
    return r;
}
__device__ __forceinline__ void wait_vm0() {
    asm volatile("s_waitcnt vmcnt(0)" ::: "memory");
    __builtin_amdgcn_sched_barrier(0);
}
__device__ __forceinline__ void wait_vm1() {
    asm volatile("s_waitcnt vmcnt(1)" ::: "memory");
    __builtin_amdgcn_sched_barrier(0);
}

// ---- grid barrier, 256 flags, PIPELINED poll: 2 snapshots in flight, check
// snapshot i while i+1 flies (vmcnt(1)); no sleep backoff. Exit drains vmcnt(0)
// before any register reuse. Producer drain (vmcnt(0)) before flag store =>
// flag visibility implies h visibility.
__device__ __forceinline__ void gbar256(unsigned* flags, int wg, unsigned target) {
    asm volatile("s_waitcnt vmcnt(0)" ::: "memory");
    if (threadIdx.x == 0)
        __hip_atomic_store(&flags[wg], target, __ATOMIC_RELAXED, __HIP_MEMORY_SCOPE_AGENT);
    if (threadIdx.x < 64) {
        const unsigned* p = flags + (threadIdx.x << 2);
        u4_ f0 = ld4u_sc(p);
        for (;;) {
            u4_ f1 = ld4u_sc(p);
            wait_vm1();
            unsigned m0 = f0[0] < f0[1] ? f0[0] : f0[1];
            unsigned m1 = f0[2] < f0[3] ? f0[2] : f0[3];
            if (__all((int)((m0 < m1 ? m0 : m1) >= target))) break;
            u4_ f2 = ld4u_sc(p);
            wait_vm1();
            m0 = f1[0] < f1[1] ? f1[0] : f1[1];
            m1 = f1[2] < f1[3] ? f1[2] : f1[3];
            if (__all((int)((m0 < m1 ? m0 : m1) >= target))) break;
            f0 = f2;
        }
        wait_vm0();   // drain dangling poll load before register reuse
    }
    __syncthreads();
}

// ---- 128-flag variant (enc: fwd and bwd halves are independent dataflows) ----
__device__ __forceinline__ void gbar128(unsigned* flags, int wg, unsigned target) {
    asm volatile("s_waitcnt vmcnt(0)" ::: "memory");
    if (threadIdx.x == 0)
        __hip_atomic_store(&flags[wg], target, __ATOMIC_RELAXED, __HIP_MEMORY_SCOPE_AGENT);
    if (threadIdx.x < 64) {
        const unsigned* p = flags + (threadIdx.x << 1);
        u2_ f0 = ld2u_sc(p);
        for (;;) {
            u2_ f1 = ld2u_sc(p);
            wait_vm1();
            unsigned mn = f0[0] < f0[1] ? f0[0] : f0[1];
            if (__all((int)(mn >= target))) break;
            u2_ f2 = ld2u_sc(p);
            wait_vm1();
            mn = f1[0] < f1[1] ? f1[0] : f1[1];
            if (__all((int)(mn >= target))) break;
            f0 = f2;
        }
        wait_vm0();
    }
    __syncthreads();
}

// ---------------- reverse source indices + barrier-flag init -----------------
__global__ void rev_idx_kernel(const int* __restrict__ src, int* __restrict__ rev,
                               unsigned* __restrict__ bars) {
    int tid = blockIdx.x * blockDim.x + threadIdx.x;
    if (tid < 512) bars[tid] = 0u;
    if (tid < BB * LKK) {
        int b = tid / LKK, t = tid % LKK;
        rev[tid] = src[b * LKK + (LKK - 1 - t)];
    }
}

// ---------------- split-bf16 MFMA NT GEMM core -------------------------------
typedef __attribute__((ext_vector_type(8))) short bfrag8;   // 8 bf16 (4 VGPR)
typedef __attribute__((ext_vector_type(4))) float facc4;    // 4 fp32 accum

__device__ __forceinline__ unsigned short f2bf(float x) {
    unsigned u = __float_as_uint(x);
    unsigned r = (u + 0x7fffu + ((u >> 16) & 1u)) >> 16;   // round-to-nearest-even
    return (unsigned short)r;
}

#define ASTR 40   // LDS row stride in bf16 elems: 80B rows -> 16B-aligned b128

__device__ __forceinline__ void gemm_core(
        short* __restrict__ Ah, short* __restrict__ Al,
        short* __restrict__ Bh, short* __restrict__ Bl,
        const float* __restrict__ A, const int* __restrict__ gidx, int lda,
        const float* __restrict__ Bw, int ldb,
        const float* __restrict__ bias,
        float* __restrict__ C, int ldc,
        int N, int K, int act, int m0, int n0) {
    int tid = threadIdx.x;
    int lane = tid & 63, w = tid >> 6;
    int wr = w >> 1, wc = w & 1;                  // wave's 64x64 quadrant
    int fr = lane & 15, fg = lane >> 4;           // fragment row/col, k-group

    int sr = tid >> 1, sc = (tid & 1) << 4;
    long abase = gidx ? (long)gidx[m0 + sr] * lda : (long)(m0 + sr) * lda;
    int gn = n0 + sr;
    bool bval = gn < N;
    long bbase = (long)gn * ldb;

    facc4 acc[4][4] = {};

    for (int k0 = 0; k0 < K; k0 += 32) {
        // ---- stage A tile (fp32 -> bf16 hi/lo) ----
        {
            float v[16];
            if (k0 + sc + 16 <= K) {
                const float* ap = A + abase + k0 + sc;
                float4 t0 = *(const float4*)(ap + 0);
                float4 t1 = *(const float4*)(ap + 4);
                float4 t2 = *(const float4*)(ap + 8);
                float4 t3 = *(const float4*)(ap + 12);
                v[0]=t0.x; v[1]=t0.y; v[2]=t0.z;  v[3]=t0.w;
                v[4]=t1.x; v[5]=t1.y; v[6]=t1.z;  v[7]=t1.w;
                v[8]=t2.x; v[9]=t2.y; v[10]=t2.z; v[11]=t2.w;
                v[12]=t3.x; v[13]=t3.y; v[14]=t3.z; v[15]=t3.w;
            } else {
#pragma unroll
                for (int c = 0; c < 16; c++) {
                    int k = k0 + sc + c;
                    v[c] = (k < K) ? A[abase + k] : 0.f;
                }
            }
            bfrag8 h0, h1, l0, l1;
#pragma unroll
            for (int c = 0; c < 8; c++) {
                unsigned short hb = f2bf(v[c]);
                float hf = __uint_as_float(((unsigned)hb) << 16);
                h0[c] = (short)hb; l0[c] = (short)f2bf(v[c] - hf);
            }
#pragma unroll
            for (int c = 0; c < 8; c++) {
                unsigned short hb = f2bf(v[8 + c]);
                float hf = __uint_as_float(((unsigned)hb) << 16);
                h1[c] = (short)hb; l1[c] = (short)f2bf(v[8 + c] - hf);
            }
            *(bfrag8*)&Ah[sr * ASTR + sc]     = h0;
            *(bfrag8*)&Ah[sr * ASTR + sc + 8] = h1;
            *(bfrag8*)&Al[sr * ASTR + sc]     = l0;
            *(bfrag8*)&Al[sr * ASTR + sc + 8] = l1;
        }
        // ---- stage B tile ----
        {
            float v[16];
            if (bval && (k0 + sc + 16 <= K)) {
                const float* bp = Bw + bbase + k0 + sc;
                float4 t0 = *(const float4*)(bp + 0);
                float4 t1 = *(const float4*)(bp + 4);
                float4 t2 = *(const float4*)(bp + 8);
                float4 t3 = *(const float4*)(bp + 12);
                v[0]=t0.x; v[1]=t0.y; v[2]=t0.z;  v[3]=t0.w;
                v[4]=t1.x; v[5]=t1.y; v[6]=t1.z;  v[7]=t1.w;
                v[8]=t2.x; v[9]=t2.y; v[10]=t2.z; v[11]=t2.w;
                v[12]=t3.x; v[13]=t3.y; v[14]=t3.z; v[15]=t3.w;
            } else {
#pragma unroll
                for (int c = 0; c < 16; c++) {
                    int k = k0 + sc + c;
                    v[c] = (bval && k < K) ? Bw[bbase + k] : 0.f;
                }
            }
            bfrag8 h0, h1, l0, l1;
#pragma unroll
            for (int c = 0; c < 8; c++) {
                unsigned short hb = f2bf(v[c]);
                float hf = __uint_as_float(((unsigned)hb) << 16);
                h0[c] = (short)hb; l0[c] = (short)f2bf(v[c] - hf);
            }
#pragma unroll
            for (int c = 0; c < 8; c++) {
                unsigned short hb = f2bf(v[8 + c]);
                float hf = __uint_as_float(((unsigned)hb) << 16);
                h1[c] = (short)hb; l1[c] = (short)f2bf(v[8 + c] - hf);
            }
            *(bfrag8*)&Bh[sr * ASTR + sc]     = h0;
            *(bfrag8*)&Bh[sr * ASTR + sc + 8] = h1;
            *(bfrag8*)&Bl[sr * ASTR + sc]     = l0;
            *(bfrag8*)&Bl[sr * ASTR + sc + 8] = l1;
        }
        __syncthreads();

        bfrag8 ah[4], al[4], bh[4], bl[4];
#pragma unroll
        for (int i = 0; i < 4; i++) {
            int ar = wr * 64 + i * 16 + fr;
            ah[i] = *(const bfrag8*)&Ah[ar * ASTR + fg * 8];
            al[i] = *(const bfrag8*)&Al[ar * ASTR + fg * 8];
            int br = wc * 64 + i * 16 + fr;
            bh[i] = *(const bfrag8*)&Bh[br * ASTR + fg * 8];
            bl[i] = *(const bfrag8*)&Bl[br * ASTR + fg * 8];
        }
#pragma unroll
        for (int i = 0; i < 4; i++)
#pragma unroll
            for (int j = 0; j < 4; j++) {
                acc[i][j] = __builtin_amdgcn_mfma_f32_16x16x32_bf16(ah[i], bh[j], acc[i][j], 0, 0, 0);
                acc[i][j] = __builtin_amdgcn_mfma_f32_16x16x32_bf16(ah[i], bl[j], acc[i][j], 0, 0, 0);
                acc[i][j] = __builtin_amdgcn_mfma_f32_16x16x32_bf16(al[i], bh[j], acc[i][j], 0, 0, 0);
            }
        __syncthreads();
    }

#pragma unroll
    for (int i = 0; i < 4; i++) {
        int row = m0 + wr * 64 + i * 16 + fg * 4;
#pragma unroll
        for (int j = 0; j < 4; j++) {
            int col = n0 + wc * 64 + j * 16 + fr;
            if (col < N) {
                float bz = bias[col];
#pragma unroll
                for (int q = 0; q < 4; q++) {
                    float vv = acc[i][j][q] + bz;
                    if (act == 1) vv = tanhf(vv);
                    C[(long)(row + q) * ldc + col] = vv;
                }
            }
        }
    }
}

__global__ __launch_bounds__(256)
void gemm_mfma128(const float* __restrict__ A, const int* __restrict__ gidx, int lda,
                  const float* __restrict__ Bw, int ldb,
                  const float* __restrict__ bias,
                  float* __restrict__ C, int ldc,
                  int N, int K, int act) {
    __shared__ __align__(16) short Ah[128 * ASTR];
    __shared__ __align__(16) short Al[128 * ASTR];
    __shared__ __align__(16) short Bh[128 * ASTR];
    __shared__ __align__(16) short Bl[128 * ASTR];
    gemm_core(Ah, Al, Bh, Bl, A, gidx, lda, Bw, ldb, bias, C, ldc, N, K, act,
              blockIdx.x * 128, blockIdx.y * 128);
}

// K and V projections fused into one 128-block dispatch (2x concurrency)
__global__ __launch_bounds__(256)
void gemm_kv(const float* __restrict__ enc_out,
             const float* __restrict__ kW, const float* __restrict__ kb,
             const float* __restrict__ vW, const float* __restrict__ vb,
             float* __restrict__ Kbuf, float* __restrict__ Vbuf) {
    __shared__ __align__(16) short Ah[128 * ASTR];
    __shared__ __align__(16) short Al[128 * ASTR];
    __shared__ __align__(16) short Bh[128 * ASTR];
    __shared__ __align__(16) short Bl[128 * ASTR];
    int ny = blockIdx.y;
    if (ny < 8)
        gemm_core(Ah, Al, Bh, Bl, enc_out, nullptr, H2, kW, H2, kb, Kbuf, H2,
                  H2, H2, 0, blockIdx.x * 128, ny * 128);
    else
        gemm_core(Ah, Al, Bh, Bl, enc_out, nullptr, H2, vW, H2, vb, Vbuf, H2,
                  H2, H2, 0, blockIdx.x * 128, (ny - 8) * 128);
}

// three xg precompute GEMMs fused into one 512-block dispatch
__global__ __launch_bounds__(256)
void gemm_xg(const float* __restrict__ emb,
             const int* __restrict__ src, const int* __restrict__ rev,
             const int* __restrict__ prev,
             const float* __restrict__ Wf, const float* __restrict__ bf,
             const float* __restrict__ Wb, const float* __restrict__ bb,
             const float* __restrict__ Wd, const float* __restrict__ bd,
             float* __restrict__ xf, float* __restrict__ xb,
             float* __restrict__ xd) {
    __shared__ __align__(16) short Ah[128 * ASTR];
    __shared__ __align__(16) short Al[128 * ASTR];
    __shared__ __align__(16) short Bh[128 * ASTR];
    __shared__ __align__(16) short Bl[128 * ASTR];
    int ny = blockIdx.y;
    if (ny < 16)
        gemm_core(Ah, Al, Bh, Bl, emb, src, DD, Wf, DD, bf, xf, G4,
                  G4, DD, 0, blockIdx.x * 128, ny * 128);
    else if (ny < 32)
        gemm_core(Ah, Al, Bh, Bl, emb, rev, DD, Wb, DD, bb, xb, G4,
                  G4, DD, 0, blockIdx.x * 128, (ny - 16) * 128);
    else
        gemm_core(Ah, Al, Bh, Bl, emb, prev, DD, Wd, DD, bd, xd, G8,
                  G8, DD, 0, blockIdx.x * 128, (ny - 32) * 128);
}

// ============ persistent encoder recurrence (fwd+bwd), 256 blocks x 256 =====
// fwd (wg<128) and bwd (wg>=128) are independent dataflows -> split barriers
// (gbar128 over each half's flags). Pipelined poll; deferred enc_out stores.
__global__ __launch_bounds__(256, 1)
void enc_recur(const float* __restrict__ xg_f, const float* __restrict__ xg_b,
               const float* __restrict__ Wf, const float* __restrict__ Wb,
               float* __restrict__ hglob, float* __restrict__ enc_out,
               float* __restrict__ encc, unsigned* __restrict__ flags) {
    __shared__ float hs[HH * 16];          // 32 KB
    __shared__ float red[256 * 33];        // 33 KB transpose-reduce scratch
    __shared__ float g256[256];
    __shared__ float hout[64];
    int wg  = blockIdx.x;
    int dir = wg >> 7;
    int j0  = (wg & 127) * 4;
    int tid = threadIdx.x;
    int ks   = tid & 31;
    int tile = tid >> 5;
    int bh   = tile >> 2;
    int gate = tile & 3;
    int sw   = (ks >> 2) & 3;
    const float* W  = dir ? Wb : Wf;    // [2048][512]
    const float* xg = dir ? xg_b : xg_f;
    unsigned* fl = flags + (dir << 7);  // this direction's 128 flags
    int wgl = wg & 127;

    float wreg[4][16];
#pragma unroll
    for (int jn = 0; jn < 4; jn++) {
        const float* wrow = W + (long)(gate * HH + j0 + jn) * HH;
#pragma unroll
        for (int j = 0; j < 16; j++) wreg[jn][j] = wrow[ks + 32 * j];
    }

    int ub = tid & 15, ujj = tid >> 4;
    int xb = tid >> 4, xgate = (tid >> 2) & 3, xjn = tid & 3;
    float creg = 0.f;
    float4* hsv = (float4*)hs;

    for (int t = 0; t < LKK; t++) {
        float acc[8][4];
#pragma unroll
        for (int i = 0; i < 8; i++)
#pragma unroll
            for (int jn = 0; jn < 4; jn++) acc[i][jn] = 0.f;

        auto do_fma = [&](int jlo, int jhi) {
#pragma unroll
            for (int j = jlo; j < jhi; j++) {
                int k = ks + 32 * j;
                float4 h0 = hsv[k * 4 + ((bh * 2 + 0) ^ sw)];
                float4 h1 = hsv[k * 4 + ((bh * 2 + 1) ^ sw)];
#pragma unroll
                for (int jn = 0; jn < 4; jn++) {
                    float w = wreg[jn][j];
                    acc[0][jn] += h0.x * w; acc[1][jn] += h0.y * w;
                    acc[2][jn] += h0.z * w; acc[3][jn] += h0.w * w;
                    acc[4][jn] += h1.x * w; acc[5][jn] += h1.y * w;
                    acc[6][jn] += h1.z * w; acc[7][jn] += h1.w * w;
                }
            }
        };

        float xval = xg[(long)(xb * LKK + t) * G4 + xgate * HH + j0 + xjn];

        if (t == 0) {
            for (int i = tid; i < HH * 16; i += 256) hs[i] = 0.f;
            __syncthreads();
            do_fma(0, 16);
        } else {
            const float* hg = hglob + (long)((dir << 1) | (t & 1)) * (HH * 16);
            f4_ vv[8];
#pragma unroll
            for (int u = 0; u < 8; u++) vv[u] = ld4_sc(hg + tid * 4 + u * 1024);
            asm volatile("s_waitcnt vmcnt(4)" ::: "memory");
            __builtin_amdgcn_sched_barrier(0);
#pragma unroll
            for (int u = 0; u < 4; u++) {
                int e = tid * 4 + u * 1024;
                int jj = e >> 4, b0 = e & 15;
                *(f4_*)&hs[(jj << 4) + ((((b0 >> 2) ^ ((jj >> 2) & 3))) << 2)] = vv[u];
            }
            __syncthreads();
            do_fma(0, 8);          // rows < 256; rows >= 256 still in flight
            wait_vm0();
#pragma unroll
            for (int u = 4; u < 8; u++) {
                int e = tid * 4 + u * 1024;
                int jj = e >> 4, b0 = e & 15;
                *(f4_*)&hs[(jj << 4) + ((((b0 >> 2) ^ ((jj >> 2) & 3))) << 2)] = vv[u];
            }
            __syncthreads();
            do_fma(8, 16);
        }

        // transpose-reduce: row r = (b*16 + gate*4 + jn), col = ks
#pragma unroll
        for (int i = 0; i < 8; i++)
#pragma unroll
            for (int jn = 0; jn < 4; jn++)
                red[((bh * 8 + i) * 16 + gate * 4 + jn) * 33 + ks] = acc[i][jn];
        __syncthreads();
        {
            const float* row = red + tid * 33;
            float s0 = 0.f, s1 = 0.f, s2 = 0.f, s3 = 0.f;
#pragma unroll
            for (int u = 0; u < 8; u++) {
                s0 += row[u * 4 + 0]; s1 += row[u * 4 + 1];
                s2 += row[u * 4 + 2]; s3 += row[u * 4 + 3];
            }
            g256[tid] = ((s0 + s1) + (s2 + s3)) + xval;
        }
        __syncthreads();

        if (tid < 64) {
            int j = j0 + ujj;
            float gi = g256[ub * 16 + 0  + ujj];
            float gf = g256[ub * 16 + 4  + ujj];
            float gg = g256[ub * 16 + 8  + ujj];
            float go = g256[ub * 16 + 12 + ujj];
            float cv = sigmoidf_(gf) * creg + sigmoidf_(gi) * tanhf(gg);
            creg = cv;
            float hv = sigmoidf_(go) * tanhf(cv);
            st_sc(&hglob[(long)((dir << 1) | ((t + 1) & 1)) * (HH * 16) + j * 16 + ub], hv);
            hout[tid] = hv;
            if (t == LKK - 1) encc[(dir * BB + ub) * HH + j] = creg;
        }
        if (t < LKK - 1) gbar128(fl, wgl, (unsigned)(t + 1));
        else __syncthreads();
        // deferred output store by wave 1 (drains at next barrier entry)
        if (tid >= 64 && tid < 128) {
            int lt = tid - 64;
            int j = j0 + (lt >> 4);
            int kpos = dir ? (LKK - 1 - t) : t;
            enc_out[(long)((lt & 15) * LKK + kpos) * H2 + dir * HH + j] = hout[lt];
        }
    }
}

// ============ persistent decoder recurrence, 256 blocks x 256 ===============
__global__ __launch_bounds__(256, 1)
void dec_recur(const float* __restrict__ xg_d, const float* __restrict__ Wd,
               const float* __restrict__ enc_out, const float* __restrict__ encc,
               float* __restrict__ hglob, float* __restrict__ Qout,
               unsigned* __restrict__ flags) {
    __shared__ float hs[HH * 16];          // 32 KB (one half of h)
    __shared__ float red[256 * 33];        // 33 KB
    __shared__ float g256[256];
    __shared__ float hout[64];
    int wg  = blockIdx.x;
    int j0  = wg * 4;
    int tid = threadIdx.x;
    int ks   = tid & 31;
    int tile = tid >> 5;
    int bh   = tile >> 2;
    int gate = tile & 3;
    int sw   = (ks >> 2) & 3;

    float wreg[4][32];
#pragma unroll
    for (int jn = 0; jn < 4; jn++) {
        const float* wrow = Wd + (long)(gate * H2 + j0 + jn) * H2;
#pragma unroll
        for (int j = 0; j < 32; j++) wreg[jn][j] = wrow[ks + 32 * j];
    }

    int ub = tid & 15, ujj = tid >> 4;
    int xb = tid >> 4, xgate = (tid >> 2) & 3, xjn = tid & 3;
    float creg = 0.f;
    if (tid < 64) {
        int j = j0 + ujj;
        creg = ((j & 1) == 0) ? encc[ub * HH + (j >> 1)]
                              : encc[(BB + ub) * HH + (j >> 1)];
    }
    float4* hsv = (float4*)hs;

    for (int t = 0; t < LQQ; t++) {
        float xval = xg_d[(long)(xb * LQQ + t) * G8 + xgate * H2 + j0 + xjn];
        float acc[8][4];
#pragma unroll
        for (int i = 0; i < 8; i++)
#pragma unroll
            for (int jn = 0; jn < 4; jn++) acc[i][jn] = 0.f;

        auto do_fma = [&](int half) {
#pragma unroll
            for (int jj2 = 0; jj2 < 16; jj2++) {
                int j = half * 16 + jj2;
                int kl = ks + 32 * jj2;
                float4 h0 = hsv[kl * 4 + ((bh * 2 + 0) ^ sw)];
                float4 h1 = hsv[kl * 4 + ((bh * 2 + 1) ^ sw)];
#pragma unroll
                for (int jn = 0; jn < 4; jn++) {
                    float w = wreg[jn][j];
                    acc[0][jn] += h0.x * w; acc[1][jn] += h0.y * w;
                    acc[2][jn] += h0.z * w; acc[3][jn] += h0.w * w;
                    acc[4][jn] += h1.x * w; acc[5][jn] += h1.y * w;
                    acc[6][jn] += h1.z * w; acc[7][jn] += h1.w * w;
                }
            }
        };

        if (t == 0) {
            for (int half = 0; half < 2; half++) {
                for (int e = tid; e < HH * 16; e += 256) {
                    int kl = e >> 4, b = e & 15;
                    int k = half * HH + kl;
                    float hv = ((k & 1) == 0)
                        ? enc_out[(long)(b * LKK + (LKK - 1)) * H2 + (k >> 1)]
                        : enc_out[(long)(b * LKK) * H2 + HH + (k >> 1)];
                    hs[(kl << 4) + ((((b >> 2) ^ ((kl >> 2) & 3))) << 2) + (b & 3)] = hv;
                }
                __syncthreads();
                do_fma(half);
                __syncthreads();
            }
        } else {
            const float* hgA = hglob + (long)(t & 1) * (H2 * 16);
            f4_ vvA[8], vvB[8];
#pragma unroll
            for (int u = 0; u < 8; u++) vvA[u] = ld4_sc(hgA + tid * 4 + u * 1024);
#pragma unroll
            for (int u = 0; u < 8; u++) vvB[u] = ld4_sc(hgA + (HH * 16) + tid * 4 + u * 1024);
            asm volatile("s_waitcnt vmcnt(8)" ::: "memory");   // A done, B in flight
            __builtin_amdgcn_sched_barrier(0);
#pragma unroll
            for (int u = 0; u < 8; u++) {
                int e = tid * 4 + u * 1024;
                int kl = e >> 4, b0 = e & 15;
                *(f4_*)&hs[(kl << 4) + ((((b0 >> 2) ^ ((kl >> 2) & 3))) << 2)] = vvA[u];
            }
            __syncthreads();
            do_fma(0);
            __syncthreads();
            wait_vm0();
#pragma unroll
            for (int u = 0; u < 8; u++) {
                int e = tid * 4 + u * 1024;
                int kl = e >> 4, b0 = e & 15;
                *(f4_*)&hs[(kl << 4) + ((((b0 >> 2) ^ ((kl >> 2) & 3))) << 2)] = vvB[u];
            }
            __syncthreads();
            do_fma(1);
        }

        // transpose-reduce
#pragma unroll
        for (int i = 0; i < 8; i++)
#pragma unroll
            for (int jn = 0; jn < 4; jn++)
                red[((bh * 8 + i) * 16 + gate * 4 + jn) * 33 + ks] = acc[i][jn];
        __syncthreads();
        {
            const float* row = red + tid * 33;
            float s0 = 0.f, s1 = 0.f, s2 = 0.f, s3 = 0.f;
#pragma unroll
            for (int u = 0; u < 8; u++) {
                s0 += row[u * 4 + 0]; s1 += row[u * 4 + 1];
                s2 += row[u * 4 + 2]; s3 += row[u * 4 + 3];
            }
            g256[tid] = ((s0 + s1) + (s2 + s3)) + xval;
        }
        __syncthreads();

        if (tid < 64) {
            int j = j0 + ujj;
            float gi = g256[ub * 16 + 0  + ujj];
            float gf = g256[ub * 16 + 4  + ujj];
            float gg = g256[ub * 16 + 8  + ujj];
            float go = g256[ub * 16 + 12 + ujj];
            float cv = sigmoidf_(gf) * creg + sigmoidf_(gi) * tanhf(gg);
            creg = cv;
            float hv = sigmoidf_(go) * tanhf(cv);
            st_sc(&hglob[(long)((t + 1) & 1) * (H2 * 16) + j * 16 + ub], hv);
            hout[tid] = hv;
        }
        if (t < LQQ - 1) gbar256(flags, wg, (unsigned)(t + 1));
        else __syncthreads();
        // deferred Qout store by wave 1 (drains at next barrier entry)
        if (tid >= 64 && tid < 128) {
            int lt = tid - 64;
            int j = j0 + (lt >> 4);
            Qout[(long)((lt & 15) * LQQ + t) * H2 + j] = hout[lt];
        }
    }
}

// ---------------- attention + concat[ctx, Q] ---------------------------------
__global__ __launch_bounds__(256)
void attention_kernel(const float* __restrict__ Qm, const float* __restrict__ Km,
                      const float* __restrict__ Vm, const int* __restrict__ source,
                      float* __restrict__ concatBuf) {
    int b = blockIdx.x >> 6;
    int q = blockIdx.x & 63;
    int tid = threadIdx.x;
    __shared__ float qrow[H2];
    __shared__ float part[LKK][4];
    __shared__ float aw[LKK];

    for (int i = tid; i < H2; i += 256) qrow[i] = Qm[(long)(b * LQQ + q) * H2 + i];
    __syncthreads();

    int k = tid >> 2, p = tid & 3;
    {
        const float* krow = Km + (long)(b * LKK + k) * H2 + p * 256;
        const float* qp = qrow + p * 256;
        float s = 0.f;
#pragma unroll 4
        for (int i = 0; i < 256; i++) s += qp[i] * krow[i];
        part[k][p] = s;
    }
    __syncthreads();
    if (tid < 64) {
        float sc = part[tid][0] + part[tid][1] + part[tid][2] + part[tid][3];
        bool masked = (source[b * LKK + tid] == 0);
        float m = masked ? -INFINITY : sc;
#pragma unroll
        for (int o = 32; o >= 1; o >>= 1) m = fmaxf(m, __shfl_xor(m, o, 64));
        float e = masked ? 0.f : expf(sc - m);
        float sum = e;
#pragma unroll
        for (int o = 32; o >= 1; o >>= 1) sum += __shfl_xor(sum, o, 64);
        aw[tid] = e / sum;
    }
    __syncthreads();

    for (int c = tid; c < H2; c += 256) {
        float acc = 0.f;
#pragma unroll 8
        for (int kk = 0; kk < LKK; kk++) acc += aw[kk] * Vm[(long)(b * LKK + kk) * H2 + c];
        long row = (long)(b * LQQ + q) * (2 * H2);
        concatBuf[row + c] = acc;
        concatBuf[row + H2 + c] = qrow[c];
    }
}

// ---------------- host launcher ----------------------------------------------
extern "C" void kernel_launch(void* const* d_in, const int* in_sizes, int n_in,
                              void* d_out, int out_size, void* d_ws, size_t ws_size,
                              hipStream_t stream) {
    const int*   src       = (const int*)  d_in[0];
    const int*   prev      = (const int*)  d_in[1];
    const float* emb       = (const float*)d_in[2];
    const float* enc_f_Wih = (const float*)d_in[3];
    const float* enc_f_Whh = (const float*)d_in[4];
    const float* enc_f_b   = (const float*)d_in[5];
    const float* enc_b_Wih = (const float*)d_in[6];
    const float* enc_b_Whh = (const float*)d_in[7];
    const float* enc_b_b   = (const float*)d_in[8];
    const float* dec_Wih   = (const float*)d_in[9];
    const float* dec_Whh   = (const float*)d_in[10];
    const float* dec_b     = (const float*)d_in[11];
    const float* k_W  = (const float*)d_in[12];
    const float* k_b  = (const float*)d_in[13];
    const float* v_W  = (const float*)d_in[14];
    const float* v_b  = (const float*)d_in[15];
    const float* fc1_W = (const float*)d_in[16];
    const float* fc1_b = (const float*)d_in[17];
    const float* fc2_W = (const float*)d_in[18];
    const float* fc2_b = (const float*)d_in[19];
    float* out = (float*)d_out;

    // workspace layout (floats)
    float* p = (float*)d_ws;
    float* xg_f    = p; p += (long)BB * LKK * G4;
    float* xg_b    = p; p += (long)BB * LKK * G4;
    float* xg_d    = p; p += (long)BB * LQQ * G8;
    float* enc_out = p; p += (long)BB * LKK * H2;
    float* encc    = p; p += 2L * BB * HH;
    float* hg_enc  = p; p += 2L * 2 * HH * 16;
    float* hg_dec  = p; p += 2L * H2 * 16;
    float* Qbuf    = p; p += (long)BB * LQQ * H2;
    float* Kbuf    = p; p += (long)BB * LKK * H2;
    float* Vbuf    = p; p += (long)BB * LKK * H2;
    float* concatB = p; p += (long)BB * LQQ * 2 * H2;
    float* fc1out  = p; p += (long)BB * LQQ * H2;
    int*   rev     = (int*)p; p += (BB * LKK);
    unsigned* bars = (unsigned*)p; p += 512;     // flags: enc [0:256), dec [256:512)

    // 1) reversed source indices + barrier-flag zero
    rev_idx_kernel<<<4, 256, 0, stream>>>(src, rev, bars);

    // 2) xg precomputes, fused into one 512-block dispatch
    gemm_xg<<<dim3(8, 64), 256, 0, stream>>>(emb, src, rev, prev,
                                             enc_f_Wih, enc_f_b,
                                             enc_b_Wih, enc_b_b,
                                             dec_Wih, dec_b,
                                             xg_f, xg_b, xg_d);

    // 3) encoder recurrence: persistent, 256 blocks x 256 threads
    enc_recur<<<dim3(256), dim3(256), 0, stream>>>(xg_f, xg_b, enc_f_Whh, enc_b_Whh,
                                                   hg_enc, enc_out, encc, bars);

    // 4) K/V projections fused (128 blocks)
    gemm_kv<<<dim3(8, 16), 256, 0, stream>>>(enc_out, k_W, k_b, v_W, v_b, Kbuf, Vbuf);

    // 5) decoder recurrence: persistent, 256 blocks x 256 threads
    dec_recur<<<dim3(256), dim3(256), 0, stream>>>(xg_d, dec_Whh, enc_out, encc,
                                                   hg_dec, Qbuf, bars + 256);

    // 6) attention -> concat[ctx, Q]
    attention_kernel<<<BB * LQQ, 256, 0, stream>>>(Qbuf, Kbuf, Vbuf, src, concatB);

    // 7) fc1 with tanh
    gemm_mfma128<<<dim3(8, 8), 256, 0, stream>>>(concatB, nullptr, 2 * H2, fc1_W, 2 * H2,
                                                 fc1_b, fc1out, H2, H2, 2 * H2, 1);

    // 8) fc2 -> output [1024, 10000]
    gemm_mfma128<<<dim3(8, (VV + 127) / 128), 256, 0, stream>>>(fc1out, nullptr, H2, fc2_W, H2,
                                                                fc2_b, out, VV, VV, H2, 0);
}